// Round 1
// baseline (2597.041 us; speedup 1.0000x reference)
//
#include <hip/hip_runtime.h>
#include <hip/hip_bf16.h>

// ---------------------------------------------------------------------------
// DispEstimator pipeline, MFMA bf16 implicit-GEMM (R8).
// R8: corr_k split into blur_k (separable 7x7 gaussian -> fp16 global,
// group-major planes) + corr2_k (23.2KB LDS, 16 barriers, launch_bounds
// (256,4) -> 16 waves/CU vs previous 65.4KB/32-barrier/11%-occupancy kernel).
// ---------------------------------------------------------------------------

typedef __attribute__((ext_vector_type(8))) short short8;
typedef __attribute__((ext_vector_type(4))) float f32x4;

__device__ __forceinline__ float s2f(short s) {
    unsigned int u = ((unsigned int)(unsigned short)s) << 16;
    float f; __builtin_memcpy(&f, &u, 4); return f;
}
__device__ __forceinline__ short f2s(float f) {
    __hip_bfloat16 h = __float2bfloat16(f);
    short s; __builtin_memcpy(&s, &h, 2); return s;
}
__device__ __forceinline__ float h2f(short s) {
    _Float16 h; __builtin_memcpy(&h, &s, 2); return (float)h;
}
__device__ __forceinline__ short f2h(float f) {
    _Float16 h = (_Float16)f;
    short s; __builtin_memcpy(&s, &h, 2); return s;
}

__device__ __forceinline__ float gw(int j) {
    const float G[7] = {0.0366329f, 0.1112808f, 0.2167453f, 0.2706821f,
                        0.2167453f, 0.1112808f, 0.0366329f};
    return G[j];
}

// ---------------------------------------------------------------------------
// NCHW fp32 -> NHWC bf16 transpose. grid (1024, B), block 256.
// ---------------------------------------------------------------------------
__global__ __launch_bounds__(256) void transpose_k(const float* __restrict__ in,
                                                   short* __restrict__ out)
{
    __shared__ float t[64][65];
    const int b = blockIdx.y;
    const int px0 = blockIdx.x * 64;
    #pragma unroll
    for (int k = 0; k < 16; ++k) {
        int idx = threadIdx.x + k * 256;
        int c = idx >> 6, x = idx & 63;
        t[c][x] = in[(size_t)(b * 64 + c) * 65536 + px0 + x];
    }
    __syncthreads();
    #pragma unroll
    for (int k = 0; k < 16; ++k) {
        int idx = threadIdx.x + k * 256;
        int px = idx >> 6, c = idx & 63;
        out[(size_t)(b * 65536 + px0 + px) * 64 + c] = f2s(t[c][px]);
    }
}

// ---------------------------------------------------------------------------
// Weight repack v2: [oc][cin][3][3] fp32 -> MFMA-native
// [o16][tap][cb][lane][8] bf16 (o16 = oc/16, cb = k-block of 32, lane=q*16+n16;
// element (lane,c8) <-> oc = o16*16+n16, ic = cb*32+q*8+c8). Zero-padded.
// ---------------------------------------------------------------------------
__global__ __launch_bounds__(256) void repack2_k(const float* __restrict__ w,
                                                 short* __restrict__ o,
                                                 int cout, int cin, int CINP)
{
    int idx = blockIdx.x * 256 + threadIdx.x;
    int CB = CINP >> 5;
    int tot = cout * 9 * CINP;
    if (idx >= tot) return;
    int c8   = idx & 7;
    int lane = (idx >> 3) & 63;
    int rest = idx >> 9;          // ((o16*9+tap)*CB + cb)
    int cb   = rest % CB;
    int rest2 = rest / CB;
    int tap  = rest2 % 9;
    int o16  = rest2 / 9;
    int n16 = lane & 15, q = lane >> 4;
    int oc = o16 * 16 + n16;
    int ic = cb * 32 + q * 8 + c8;
    float v = (ic < cin) ? w[(size_t)(oc * cin + ic) * 9 + tap] : 0.f;
    o[idx] = f2s(v);
}

// ---------------------------------------------------------------------------
// MFMA implicit-GEMM 3x3 conv, NHWC bf16, zero pad = DIL.
// Wave: G*16 px x 16*NOC oc. Block 4 waves (WX px-groups x WY oc-groups).
// Weights in MFMA-native layout (repack2_k). grid:(XT*256, cout/(16*NOC*WY), nb)
// ---------------------------------------------------------------------------
template<int DIL, int CINP, int WY, int NOC, int G>
__global__ __launch_bounds__(256) void convmfma_k(
    const short* __restrict__ srcA, const short* __restrict__ srcB,
    int splitK, int csA, int csB,
    const short* __restrict__ wgt, const float* __restrict__ bias,
    short* __restrict__ out, int OSTR, int OBASE, int b0)
{
    constexpr int WX  = 4 / WY;
    constexpr int PXW = G * 16;
    constexpr int PXB = PXW * WX;
    constexpr int XT  = 256 / PXB;
    constexpr int CB  = CINP / 32;

    const int lane = threadIdx.x & 63;
    const int wave = threadIdx.x >> 6;
    const int q = lane >> 4, n16 = lane & 15;
    const int wx = wave % WX, wy = wave / WX;
    const int xt = blockIdx.x % XT;
    const int y  = blockIdx.x / XT;
    const int b  = b0 + blockIdx.z;
    const int ocWaveBase = blockIdx.y * (16 * NOC * WY) + wy * (16 * NOC);
    const int o16base = ocWaveBase >> 4;
    const int x0 = xt * PXB + wx * PXW;

    f32x4 acc[G][NOC];
    #pragma unroll
    for (int g = 0; g < G; ++g)
        #pragma unroll
        for (int t = 0; t < NOC; ++t)
            acc[g][t] = {0.f, 0.f, 0.f, 0.f};

    #pragma unroll
    for (int tap = 0; tap < 9; ++tap) {
        const int dy = (tap / 3 - 1) * DIL;
        const int dx = (tap % 3 - 1) * DIL;
        const int yy = y + dy;
        const bool rowok = ((unsigned)yy < 256u);
        const int yyc = rowok ? yy : (yy < 0 ? 0 : 255);
        const int rowbase = (b * 256 + yyc) * 256;
        bool ok[G]; int xc[G];
        #pragma unroll
        for (int g = 0; g < G; ++g) {
            int xx = x0 + g * 16 + n16 + dx;
            bool xok = ((unsigned)xx < 256u);
            ok[g] = rowok && xok;
            xc[g] = xok ? xx : (xx < 0 ? 0 : 255);
        }
        #pragma unroll
        for (int cb = 0; cb < CB; ++cb) {
            const int icb = cb * 32;
            const int ic = icb + q * 8;
            const short* sp; int icc, cs;
            if (icb < splitK) { sp = srcA; icc = ic; cs = csA; }
            else              { sp = srcB; icc = ic - splitK; cs = csB; }
            short8 bfr[G];
            #pragma unroll
            for (int g = 0; g < G; ++g) {
                short8 v = *reinterpret_cast<const short8*>(
                    sp + (size_t)(rowbase + xc[g]) * cs + icc);
                if (!ok[g]) v = v ^ v;
                bfr[g] = v;
            }
            #pragma unroll
            for (int t = 0; t < NOC; ++t) {
                short8 a = *reinterpret_cast<const short8*>(
                    wgt + ((((size_t)(o16base + t) * 9 + tap) * CB + cb) * 64 + lane) * 8);
                #pragma unroll
                for (int g = 0; g < G; ++g)
                    acc[g][t] = __builtin_amdgcn_mfma_f32_16x16x32_bf16(
                        a, bfr[g], acc[g][t], 0, 0, 0);
            }
        }
    }

    #pragma unroll
    for (int g = 0; g < G; ++g) {
        const size_t px_lin = (size_t)(b * 256 + y) * 256 + x0 + g * 16 + n16;
        #pragma unroll
        for (int t = 0; t < NOC; ++t) {
            const int oc = ocWaveBase + t * 16 + q * 4;
            f32x4 v = acc[g][t];
            if (bias) {
                v.x += bias[oc];     v.y += bias[oc + 1];
                v.z += bias[oc + 2]; v.w += bias[oc + 3];
            }
            ushort4 pk;
            pk.x = (unsigned short)f2s(v.x);
            pk.y = (unsigned short)f2s(v.y);
            pk.z = (unsigned short)f2s(v.z);
            pk.w = (unsigned short)f2s(v.w);
            *reinterpret_cast<ushort4*>(out + px_lin * OSTR + OBASE + oc) = pk;
        }
    }
}

// ---------------------------------------------------------------------------
// Instance-norm partial sums, NHWC. grid (128 slices, B), block 256.
// ---------------------------------------------------------------------------
__global__ __launch_bounds__(256) void in_stats_nhwc_k(const short* __restrict__ x,
                                                       float* __restrict__ sums,
                                                       int C, int lC)
{
    __shared__ float ls[256], lss[256];
    const int tid = threadIdx.x;
    const int b = blockIdx.y;
    const int c = tid & (C - 1);
    const int sub = tid >> lC;
    const int tpc = 256 >> lC;
    const int px0 = blockIdx.x * 512;
    float s = 0.f, ss = 0.f;
    for (int p = sub; p < 512; p += tpc) {
        float v = s2f(x[(size_t)(b * 65536 + px0 + p) * C + c]);
        s += v; ss += v * v;
    }
    ls[tid] = s; lss[tid] = ss;
    __syncthreads();
    if (tid < C) {
        float s0 = ls[tid], ss0 = lss[tid];
        for (int j = 1; j < tpc; ++j) { s0 += ls[tid + j * C]; ss0 += lss[tid + j * C]; }
        atomicAdd(sums + 2 * (b * C + tid), s0);
        atomicAdd(sums + 2 * (b * C + tid) + 1, ss0);
    }
}

__global__ __launch_bounds__(256) void in_finalize_k(const float* __restrict__ sums,
                                                     float* __restrict__ stats, int n)
{
    int i = blockIdx.x * 256 + threadIdx.x;
    if (i >= n) return;
    float m = sums[2 * i] * (1.f / 65536.f);
    float var = sums[2 * i + 1] * (1.f / 65536.f) - m * m;
    if (var < 0.f) var = 0.f;
    stats[2 * i] = m;
    stats[2 * i + 1] = rsqrtf(var + 1e-5f);
}

__global__ __launch_bounds__(256) void in_apply_nhwc_k(short* __restrict__ x,
                                                       const float* __restrict__ stats,
                                                       const float* __restrict__ gamma,
                                                       const float* __restrict__ beta,
                                                       int C, int lC, int n4)
{
    int i = blockIdx.x * 256 + threadIdx.x;
    if (i >= n4) return;
    int e0 = i * 4;
    int c0 = e0 & (C - 1);
    int b = e0 >> (16 + lC);
    ushort4 u = reinterpret_cast<ushort4*>(x)[i];
    unsigned short vs[4] = {u.x, u.y, u.z, u.w};
    #pragma unroll
    for (int j = 0; j < 4; ++j) {
        int bc = b * C + c0 + j;
        float t = (s2f((short)vs[j]) - stats[2 * bc]) * stats[2 * bc + 1]
                  * gamma[c0 + j] + beta[c0 + j];
        vs[j] = (unsigned short)f2s(t >= 0.f ? t : 0.2f * t);
    }
    u.x = vs[0]; u.y = vs[1]; u.z = vs[2]; u.w = vs[3];
    reinterpret_cast<ushort4*>(x)[i] = u;
}

// ---------------------------------------------------------------------------
// Separable 7x7 gaussian blur of f1 (A ch 0-63, replicate edges) -> fp16
// planes, group-major: B1[((g*4+b)<<16 | px)*8 + c].  One (16x16 tile,
// 8-ch group) per block; grid (256*8, B), block 256. LDS 24.6 KB, 2 barriers.
// ---------------------------------------------------------------------------
__global__ __launch_bounds__(256) void blur_k(const short* __restrict__ A,
                                              short* __restrict__ B1)
{
    __shared__ __align__(16) short raw[484 * 8];    // 22x22 halo, 7.7 KB
    __shared__ __align__(16) float hb[352 * 12];    // 22 rows x 16 cols, 16.9 KB

    const int tid  = threadIdx.x;
    const int tile = blockIdx.x >> 3;
    const int g    = blockIdx.x & 7;
    const int c0   = g * 8;
    const int tx = (tile & 15) << 4;
    const int ty = (tile >> 4) << 4;
    const int b  = blockIdx.y;

    #pragma unroll
    for (int it = 0; it < 2; ++it) {
        int i = tid + it * 256;
        if (i < 484) {
            int y = i / 22, x = i - y * 22;
            int gy = ty + y - 3, gx = tx + x - 3;
            gy = gy < 0 ? 0 : (gy > 255 ? 255 : gy);
            gx = gx < 0 ? 0 : (gx > 255 ? 255 : gx);
            *reinterpret_cast<short8*>(&raw[i * 8]) =
                *reinterpret_cast<const short8*>(
                    &A[(size_t)((b << 16) + (gy << 8) + gx) * 128 + c0]);
        }
    }
    __syncthreads();

    #pragma unroll
    for (int it = 0; it < 2; ++it) {
        int i = tid + it * 256;
        if (i < 352) {                       // 22 rows x 16 core cols
            int r = i >> 4, cc = i & 15;
            float s[8];
            #pragma unroll
            for (int c = 0; c < 8; ++c) s[c] = 0.f;
            #pragma unroll
            for (int j = 0; j < 7; ++j) {
                short8 v = *reinterpret_cast<const short8*>(&raw[(r * 22 + cc + j) * 8]);
                float w = gw(j);
                #pragma unroll
                for (int c = 0; c < 8; ++c) s[c] += w * s2f(v[c]);
            }
            #pragma unroll
            for (int c = 0; c < 8; ++c) hb[i * 12 + c] = s[c];
        }
    }
    __syncthreads();

    const int py = tid >> 4, px = tid & 15;
    float s[8];
    #pragma unroll
    for (int c = 0; c < 8; ++c) s[c] = 0.f;
    #pragma unroll
    for (int j = 0; j < 7; ++j) {
        const float* hp = &hb[((py + j) * 16 + px) * 12];
        float w = gw(j);
        #pragma unroll
        for (int c = 0; c < 8; ++c) s[c] += w * hp[c];
    }
    short8 ov;
    #pragma unroll
    for (int c = 0; c < 8; ++c) ov[c] = f2h(s[c]);
    *reinterpret_cast<short8*>(
        &B1[(size_t)(((g * 4 + b) << 16) + ((ty + py) << 8) + tx + px) * 8]) = ov;
}

// ---------------------------------------------------------------------------
// Local correlation from pre-blurred f1 (fp16 planes) + f2 (A ch 64-127).
// Per 8-ch group: stage 22x22 blurred tile (zero outside image) into padded
// LDS (stride 12 floats), accumulate 49 SSDs. LDS 23.2 KB, 16 barriers.
// Block 256 = 16x16 px. Grid (256, B).
// ---------------------------------------------------------------------------
__global__ __launch_bounds__(256, 4) void corr2_k(const short* __restrict__ A,
                                                  const short* __restrict__ B1,
                                                  short* __restrict__ lcPad,
                                                  float* __restrict__ lcsum)
{
    __shared__ __align__(16) float bl[484 * 12];    // 23.2 KB
    __shared__ float red[4];

    const int tid = threadIdx.x;
    const int tx = (blockIdx.x & 15) << 4;
    const int ty = (blockIdx.x >> 4) << 4;
    const int b  = blockIdx.y;
    const int py = tid >> 4, px = tid & 15;

    float acc[49];
    #pragma unroll
    for (int k = 0; k < 49; ++k) acc[k] = 0.f;

    for (int g = 0; g < 8; ++g) {
        const int c0 = g * 8;
        const size_t plane = (size_t)(g * 4 + b) << 16;

        #pragma unroll
        for (int it = 0; it < 2; ++it) {
            int i = tid + it * 256;
            if (i < 484) {
                int y = i / 22, x = i - y * 22;
                int gy = ty + y - 3, gx = tx + x - 3;
                bool okp = (gy >= 0 && gy < 256 && gx >= 0 && gx < 256);
                f32x4 lo = {0.f, 0.f, 0.f, 0.f};
                f32x4 hi = {0.f, 0.f, 0.f, 0.f};
                if (okp) {
                    short8 v = *reinterpret_cast<const short8*>(
                        &B1[(plane + (gy << 8) + gx) * 8]);
                    lo.x = h2f(v[0]); lo.y = h2f(v[1]);
                    lo.z = h2f(v[2]); lo.w = h2f(v[3]);
                    hi.x = h2f(v[4]); hi.y = h2f(v[5]);
                    hi.z = h2f(v[6]); hi.w = h2f(v[7]);
                }
                *reinterpret_cast<f32x4*>(&bl[i * 12])     = lo;
                *reinterpret_cast<f32x4*>(&bl[i * 12 + 4]) = hi;
            }
        }
        __syncthreads();

        short8 f2v = *reinterpret_cast<const short8*>(
            &A[(size_t)((b << 16) + ((ty + py) << 8) + tx + px) * 128 + 64 + c0]);
        float f2f[8];
        #pragma unroll
        for (int c = 0; c < 8; ++c) f2f[c] = s2f(f2v[c]);

        const float* blp = &bl[(py * 22 + px) * 12];
        #pragma unroll
        for (int i = 0; i < 7; ++i)
            #pragma unroll
            for (int j = 0; j < 7; ++j) {
                const float* cell = blp + (i * 22 + j) * 12;
                f32x4 lo = *reinterpret_cast<const f32x4*>(cell);
                f32x4 hi = *reinterpret_cast<const f32x4*>(cell + 4);
                float a = acc[i * 7 + j];
                float d;
                d = f2f[0] - lo.x; a += d * d;
                d = f2f[1] - lo.y; a += d * d;
                d = f2f[2] - lo.z; a += d * d;
                d = f2f[3] - lo.w; a += d * d;
                d = f2f[4] - hi.x; a += d * d;
                d = f2f[5] - hi.y; a += d * d;
                d = f2f[6] - hi.z; a += d * d;
                d = f2f[7] - hi.w; a += d * d;
                acc[i * 7 + j] = a;
            }
        __syncthreads();
    }

    const size_t base = (size_t)((b << 16) + ((ty + py) << 8) + tx + px) * 64;
    float tot = 0.f;
    #pragma unroll
    for (int k = 0; k < 49; ++k) {
        float m = acc[k] * (1.f / 64.f);
        lcPad[base + k] = f2s(m);
        tot += m;
    }
    #pragma unroll
    for (int k = 49; k < 64; ++k) lcPad[base + k] = 0;

    for (int o = 32; o; o >>= 1) tot += __shfl_down(tot, o);
    if ((tid & 63) == 0) red[tid >> 6] = tot;
    __syncthreads();
    if (tid == 0) atomicAdd(lcsum + b, red[0] + red[1] + red[2] + red[3]);
}

__global__ __launch_bounds__(256) void lc_norm_k(short* __restrict__ lc,
                                                 const float* __restrict__ ls, int n4)
{
    int i = blockIdx.x * 256 + threadIdx.x;
    if (i >= n4) return;
    int b = (i * 4) >> 22;
    float sc = 1.f / (ls[b] * (1.f / 3211264.f) + 1e-6f);
    ushort4 u = reinterpret_cast<ushort4*>(lc)[i];
    u.x = (unsigned short)f2s(s2f((short)u.x) * sc);
    u.y = (unsigned short)f2s(s2f((short)u.y) * sc);
    u.z = (unsigned short)f2s(s2f((short)u.z) * sc);
    u.w = (unsigned short)f2s(s2f((short)u.w) * sc);
    reinterpret_cast<ushort4*>(lc)[i] = u;
}

// ---------------------------------------------------------------------------
// Head conv: NHWC bf16 [b,px,16] -> NCHW fp32 planes [b*2+oc][px].
// ---------------------------------------------------------------------------
__global__ __launch_bounds__(256) void head_k(const short* __restrict__ e3,
                                              const float* __restrict__ w,
                                              const float* __restrict__ bias,
                                              float* __restrict__ hd)
{
    int pix = blockIdx.x * 256 + threadIdx.x;
    int b = pix >> 16, rem = pix & 65535;
    int y = rem >> 8, x = rem & 255;
    float a0 = bias[0], a1 = bias[1];
    #pragma unroll
    for (int tap = 0; tap < 9; ++tap) {
        int yy = y + tap / 3 - 1, xx = x + tap % 3 - 1;
        if ((unsigned)yy >= 256u || (unsigned)xx >= 256u) continue;
        const short* p = e3 + (size_t)((b << 16) + (yy << 8) + xx) * 16;
        #pragma unroll
        for (int ic = 0; ic < 16; ++ic) {
            float v = s2f(p[ic]);
            a0 += v * w[ic * 9 + tap];
            a1 += v * w[(16 + ic) * 9 + tap];
        }
    }
    hd[(size_t)(b * 2) * 65536 + rem]     = a0;
    hd[(size_t)(b * 2 + 1) * 65536 + rem] = a1;
}

// ---------------------------------------------------------------------------
// Final separable 7-tap gaussian blur (replicate edges), fp32 planes.
// ---------------------------------------------------------------------------
__global__ __launch_bounds__(256) void blur7f_k(const float* __restrict__ in,
                                                float* __restrict__ out)
{
    __shared__ float raw[22 * 22];
    __shared__ float hb[22 * 16];
    const int tid = threadIdx.x;
    const int tx = (blockIdx.x & 15) << 4;
    const int ty = (blockIdx.x >> 4) << 4;
    const size_t ch = ((size_t)blockIdx.y) << 16;
    const int py = tid >> 4, px = tid & 15;

    for (int i = tid; i < 484; i += 256) {
        int y = i / 22, x = i - y * 22;
        int gy = ty + y - 3, gx = tx + x - 3;
        gy = gy < 0 ? 0 : (gy > 255 ? 255 : gy);
        gx = gx < 0 ? 0 : (gx > 255 ? 255 : gx);
        raw[i] = in[ch + (gy << 8) + gx];
    }
    __syncthreads();
    for (int i = tid; i < 352; i += 256) {
        int r = i >> 4, cc = i & 15;
        float s = 0.f;
        #pragma unroll
        for (int j = 0; j < 7; ++j) s += gw(j) * raw[r * 22 + cc + j];
        hb[i] = s;
    }
    __syncthreads();
    float s = 0.f;
    #pragma unroll
    for (int j = 0; j < 7; ++j) s += gw(j) * hb[(py + j) * 16 + px];
    out[ch + ((ty + py) << 8) + tx + px] = s;
}

// ---------------------------------------------------------------------------
extern "C" void kernel_launch(void* const* d_in, const int* in_sizes, int n_in,
                              void* d_out, int out_size, void* d_ws, size_t ws_size,
                              hipStream_t stream)
{
    const float* feat1  = (const float*)d_in[0];
    const float* feat2  = (const float*)d_in[1];
    const float* pre_w  = (const float*)d_in[2];
    const float* pre_b  = (const float*)d_in[3];
    const float* fc1_w  = (const float*)d_in[4];
    const float* fc1_g  = (const float*)d_in[5];
    const float* fc1_be = (const float*)d_in[6];
    const float* fc2_w  = (const float*)d_in[7];
    const float* fc2_b  = (const float*)d_in[8];
    const float* e1_w   = (const float*)d_in[9];
    const float* e1_g   = (const float*)d_in[10];
    const float* e1_be  = (const float*)d_in[11];
    const float* e2_w   = (const float*)d_in[12];
    const float* e2_g   = (const float*)d_in[13];
    const float* e2_be  = (const float*)d_in[14];
    const float* e3_w   = (const float*)d_in[15];
    const float* e3_g   = (const float*)d_in[16];
    const float* e3_be  = (const float*)d_in[17];
    const float* head_w = (const float*)d_in[18];
    const float* head_b = (const float*)d_in[19];
    float* out = (float*)d_out;

    const size_t NEED = 152000000;
    if (ws_size < NEED) return;

    char* ws = (char*)d_ws;
    short* T1      = (short*)(ws);
    short* T2      = (short*)(ws + 33554432);
    short* lcPad   = (short*)(ws);
    short* B1h     = (short*)(ws + 33554432);   // blurred f1, fp16 group-major
    short* featBuf = (short*)(ws + 33554432);
    short* A       = (short*)(ws + 67108864);
    short* FC1o    = (short*)(ws + 83886080);
    short* E1o     = (short*)(ws + 67108864);
    short* E2o     = (short*)(ws + 100663296);
    short* E3o     = (short*)(ws + 117440512);
    float* HD      = (float*)(ws + 125829120);
    short* preW    = (short*)(ws + 150994944);
    short* fc1W    = (short*)(ws + 151068672);
    short* fc2W    = (short*)(ws + 151363584);
    short* e1W     = (short*)(ws + 151511040);
    short* e2W     = (short*)(ws + 151658496);
    short* e3W     = (short*)(ws + 151695360);
    float* sums0   = (float*)(ws + 151704576);
    float* sums1   = (float*)(ws + 151708672);
    float* sums2   = (float*)(ws + 151712768);
    float* sums3   = (float*)(ws + 151716864);
    float* stats0  = (float*)(ws + 151720960);
    float* stats1  = (float*)(ws + 151725056);
    float* stats2  = (float*)(ws + 151729152);
    float* stats3  = (float*)(ws + 151733248);
    float* LS      = (float*)(ws + 151737344);

    hipMemsetAsync(ws + 151704576, 0, 32784, stream);

    transpose_k<<<dim3(1024, 4), 256, 0, stream>>>(feat1, T1);
    transpose_k<<<dim3(1024, 4), 256, 0, stream>>>(feat2, T2);

    repack2_k<<<144, 256, 0, stream>>>(pre_w, preW, 64, 64, 64);
    repack2_k<<<576, 256, 0, stream>>>(fc1_w, fc1W, 128, 128, 128);
    repack2_k<<<288, 256, 0, stream>>>(fc2_w, fc2W, 64, 128, 128);
    repack2_k<<<288, 256, 0, stream>>>(e1_w, e1W, 64, 113, 128);
    repack2_k<<<72, 256, 0, stream>>>(e2_w, e2W, 32, 64, 64);
    repack2_k<<<18, 256, 0, stream>>>(e3_w, e3W, 16, 32, 32);

    // pre conv (cout=64): G=4, NOC=4, WY=1 -> block 256px x 64oc
    convmfma_k<1, 64, 1, 4, 4><<<dim3(256, 1, 4), 256, 0, stream>>>(
        T1, T1, 64, 64, 64, preW, pre_b, A, 128, 0, 0);
    convmfma_k<1, 64, 1, 4, 4><<<dim3(256, 1, 4), 256, 0, stream>>>(
        T2, T2, 64, 64, 64, preW, pre_b, A, 128, 64, 0);

    // blur f1 -> fp16 planes, then local correlation + normalize
    blur_k<<<dim3(2048, 4), 256, 0, stream>>>(A, B1h);
    corr2_k<<<dim3(256, 4), 256, 0, stream>>>(A, B1h, lcPad, LS);
    lc_norm_k<<<16384, 256, 0, stream>>>(lcPad, LS, 4194304);

    // fc1 (cout=128): G=4, NOC=4, WY=2 -> block 128px x 128oc; batch-phased
    for (int b = 3; b >= 0; --b)
        convmfma_k<1, 128, 2, 4, 4><<<dim3(512, 1, 1), 256, 0, stream>>>(
            A, A, 128, 128, 128, fc1W, nullptr, FC1o, 128, 0, b);
    in_stats_nhwc_k<<<dim3(128, 4), 256, 0, stream>>>(FC1o, sums0, 128, 7);
    in_finalize_k<<<2, 256, 0, stream>>>(sums0, stats0, 512);
    in_apply_nhwc_k<<<32768, 256, 0, stream>>>(FC1o, stats0, fc1_g, fc1_be, 128, 7, 8388608);

    // fc2 (cout=64): G=4, NOC=4, WY=1
    convmfma_k<1, 128, 1, 4, 4><<<dim3(256, 1, 4), 256, 0, stream>>>(
        FC1o, FC1o, 128, 128, 128, fc2W, fc2_b, featBuf, 64, 0, 0);

    // e1 (cout=64): concat(featBuf, lcPad)
    convmfma_k<1, 128, 1, 4, 4><<<dim3(256, 1, 4), 256, 0, stream>>>(
        featBuf, lcPad, 64, 64, 64, e1W, nullptr, E1o, 64, 0, 0);
    in_stats_nhwc_k<<<dim3(128, 4), 256, 0, stream>>>(E1o, sums1, 64, 6);
    in_finalize_k<<<1, 256, 0, stream>>>(sums1, stats1, 256);
    in_apply_nhwc_k<<<16384, 256, 0, stream>>>(E1o, stats1, e1_g, e1_be, 64, 6, 4194304);

    // e2 (cout=32): dil=2, G=4, NOC=2
    convmfma_k<2, 64, 1, 2, 4><<<dim3(256, 1, 4), 256, 0, stream>>>(
        E1o, E1o, 64, 64, 64, e2W, nullptr, E2o, 32, 0, 0);
    in_stats_nhwc_k<<<dim3(128, 4), 256, 0, stream>>>(E2o, sums2, 32, 5);
    in_finalize_k<<<1, 256, 0, stream>>>(sums2, stats2, 128);
    in_apply_nhwc_k<<<8192, 256, 0, stream>>>(E2o, stats2, e2_g, e2_be, 32, 5, 2097152);

    // e3 (cout=16): dil=4, G=4, NOC=1
    convmfma_k<4, 32, 1, 1, 4><<<dim3(256, 1, 4), 256, 0, stream>>>(
        E2o, E2o, 32, 32, 32, e3W, nullptr, E3o, 16, 0, 0);
    in_stats_nhwc_k<<<dim3(128, 4), 256, 0, stream>>>(E3o, sums3, 16, 4);
    in_finalize_k<<<1, 256, 0, stream>>>(sums3, stats3, 64);
    in_apply_nhwc_k<<<4096, 256, 0, stream>>>(E3o, stats3, e3_g, e3_be, 16, 4, 1048576);

    head_k<<<1024, 256, 0, stream>>>(E3o, head_w, head_b, HD);
    blur7f_k<<<dim3(256, 8), 256, 0, stream>>>(HD, out);
}

// Round 2
// 1316.257 us; speedup vs baseline: 1.9731x; 1.9731x over previous
//
#include <hip/hip_runtime.h>
#include <hip/hip_bf16.h>

// ---------------------------------------------------------------------------
// DispEstimator pipeline, MFMA bf16 implicit-GEMM (R9).
// R9: fix R8 spill disaster — corr2_k's __launch_bounds__(256,4) capped VGPRs
// at 64, spilling acc[49] to scratch (4.4 GB of spill traffic, 1377us). Plain
// __launch_bounds__(256) like the old corr_k (~148 VGPR, no spill); blur split
// (blur_k -> fp16 planes) + 23.2KB-LDS corr2_k structure retained.
// ---------------------------------------------------------------------------

typedef __attribute__((ext_vector_type(8))) short short8;
typedef __attribute__((ext_vector_type(4))) float f32x4;

__device__ __forceinline__ float s2f(short s) {
    unsigned int u = ((unsigned int)(unsigned short)s) << 16;
    float f; __builtin_memcpy(&f, &u, 4); return f;
}
__device__ __forceinline__ short f2s(float f) {
    __hip_bfloat16 h = __float2bfloat16(f);
    short s; __builtin_memcpy(&s, &h, 2); return s;
}
__device__ __forceinline__ float h2f(short s) {
    _Float16 h; __builtin_memcpy(&h, &s, 2); return (float)h;
}
__device__ __forceinline__ short f2h(float f) {
    _Float16 h = (_Float16)f;
    short s; __builtin_memcpy(&s, &h, 2); return s;
}

__device__ __forceinline__ float gw(int j) {
    const float G[7] = {0.0366329f, 0.1112808f, 0.2167453f, 0.2706821f,
                        0.2167453f, 0.1112808f, 0.0366329f};
    return G[j];
}

// ---------------------------------------------------------------------------
// NCHW fp32 -> NHWC bf16 transpose. grid (1024, B), block 256.
// ---------------------------------------------------------------------------
__global__ __launch_bounds__(256) void transpose_k(const float* __restrict__ in,
                                                   short* __restrict__ out)
{
    __shared__ float t[64][65];
    const int b = blockIdx.y;
    const int px0 = blockIdx.x * 64;
    #pragma unroll
    for (int k = 0; k < 16; ++k) {
        int idx = threadIdx.x + k * 256;
        int c = idx >> 6, x = idx & 63;
        t[c][x] = in[(size_t)(b * 64 + c) * 65536 + px0 + x];
    }
    __syncthreads();
    #pragma unroll
    for (int k = 0; k < 16; ++k) {
        int idx = threadIdx.x + k * 256;
        int px = idx >> 6, c = idx & 63;
        out[(size_t)(b * 65536 + px0 + px) * 64 + c] = f2s(t[c][px]);
    }
}

// ---------------------------------------------------------------------------
// Weight repack v2: [oc][cin][3][3] fp32 -> MFMA-native
// [o16][tap][cb][lane][8] bf16 (o16 = oc/16, cb = k-block of 32, lane=q*16+n16;
// element (lane,c8) <-> oc = o16*16+n16, ic = cb*32+q*8+c8). Zero-padded.
// ---------------------------------------------------------------------------
__global__ __launch_bounds__(256) void repack2_k(const float* __restrict__ w,
                                                 short* __restrict__ o,
                                                 int cout, int cin, int CINP)
{
    int idx = blockIdx.x * 256 + threadIdx.x;
    int CB = CINP >> 5;
    int tot = cout * 9 * CINP;
    if (idx >= tot) return;
    int c8   = idx & 7;
    int lane = (idx >> 3) & 63;
    int rest = idx >> 9;          // ((o16*9+tap)*CB + cb)
    int cb   = rest % CB;
    int rest2 = rest / CB;
    int tap  = rest2 % 9;
    int o16  = rest2 / 9;
    int n16 = lane & 15, q = lane >> 4;
    int oc = o16 * 16 + n16;
    int ic = cb * 32 + q * 8 + c8;
    float v = (ic < cin) ? w[(size_t)(oc * cin + ic) * 9 + tap] : 0.f;
    o[idx] = f2s(v);
}

// ---------------------------------------------------------------------------
// MFMA implicit-GEMM 3x3 conv, NHWC bf16, zero pad = DIL.
// Wave: G*16 px x 16*NOC oc. Block 4 waves (WX px-groups x WY oc-groups).
// Weights in MFMA-native layout (repack2_k). grid:(XT*256, cout/(16*NOC*WY), nb)
// ---------------------------------------------------------------------------
template<int DIL, int CINP, int WY, int NOC, int G>
__global__ __launch_bounds__(256) void convmfma_k(
    const short* __restrict__ srcA, const short* __restrict__ srcB,
    int splitK, int csA, int csB,
    const short* __restrict__ wgt, const float* __restrict__ bias,
    short* __restrict__ out, int OSTR, int OBASE, int b0)
{
    constexpr int WX  = 4 / WY;
    constexpr int PXW = G * 16;
    constexpr int PXB = PXW * WX;
    constexpr int XT  = 256 / PXB;
    constexpr int CB  = CINP / 32;

    const int lane = threadIdx.x & 63;
    const int wave = threadIdx.x >> 6;
    const int q = lane >> 4, n16 = lane & 15;
    const int wx = wave % WX, wy = wave / WX;
    const int xt = blockIdx.x % XT;
    const int y  = blockIdx.x / XT;
    const int b  = b0 + blockIdx.z;
    const int ocWaveBase = blockIdx.y * (16 * NOC * WY) + wy * (16 * NOC);
    const int o16base = ocWaveBase >> 4;
    const int x0 = xt * PXB + wx * PXW;

    f32x4 acc[G][NOC];
    #pragma unroll
    for (int g = 0; g < G; ++g)
        #pragma unroll
        for (int t = 0; t < NOC; ++t)
            acc[g][t] = {0.f, 0.f, 0.f, 0.f};

    #pragma unroll
    for (int tap = 0; tap < 9; ++tap) {
        const int dy = (tap / 3 - 1) * DIL;
        const int dx = (tap % 3 - 1) * DIL;
        const int yy = y + dy;
        const bool rowok = ((unsigned)yy < 256u);
        const int yyc = rowok ? yy : (yy < 0 ? 0 : 255);
        const int rowbase = (b * 256 + yyc) * 256;
        bool ok[G]; int xc[G];
        #pragma unroll
        for (int g = 0; g < G; ++g) {
            int xx = x0 + g * 16 + n16 + dx;
            bool xok = ((unsigned)xx < 256u);
            ok[g] = rowok && xok;
            xc[g] = xok ? xx : (xx < 0 ? 0 : 255);
        }
        #pragma unroll
        for (int cb = 0; cb < CB; ++cb) {
            const int icb = cb * 32;
            const int ic = icb + q * 8;
            const short* sp; int icc, cs;
            if (icb < splitK) { sp = srcA; icc = ic; cs = csA; }
            else              { sp = srcB; icc = ic - splitK; cs = csB; }
            short8 bfr[G];
            #pragma unroll
            for (int g = 0; g < G; ++g) {
                short8 v = *reinterpret_cast<const short8*>(
                    sp + (size_t)(rowbase + xc[g]) * cs + icc);
                if (!ok[g]) v = v ^ v;
                bfr[g] = v;
            }
            #pragma unroll
            for (int t = 0; t < NOC; ++t) {
                short8 a = *reinterpret_cast<const short8*>(
                    wgt + ((((size_t)(o16base + t) * 9 + tap) * CB + cb) * 64 + lane) * 8);
                #pragma unroll
                for (int g = 0; g < G; ++g)
                    acc[g][t] = __builtin_amdgcn_mfma_f32_16x16x32_bf16(
                        a, bfr[g], acc[g][t], 0, 0, 0);
            }
        }
    }

    #pragma unroll
    for (int g = 0; g < G; ++g) {
        const size_t px_lin = (size_t)(b * 256 + y) * 256 + x0 + g * 16 + n16;
        #pragma unroll
        for (int t = 0; t < NOC; ++t) {
            const int oc = ocWaveBase + t * 16 + q * 4;
            f32x4 v = acc[g][t];
            if (bias) {
                v.x += bias[oc];     v.y += bias[oc + 1];
                v.z += bias[oc + 2]; v.w += bias[oc + 3];
            }
            ushort4 pk;
            pk.x = (unsigned short)f2s(v.x);
            pk.y = (unsigned short)f2s(v.y);
            pk.z = (unsigned short)f2s(v.z);
            pk.w = (unsigned short)f2s(v.w);
            *reinterpret_cast<ushort4*>(out + px_lin * OSTR + OBASE + oc) = pk;
        }
    }
}

// ---------------------------------------------------------------------------
// Instance-norm partial sums, NHWC. grid (128 slices, B), block 256.
// ---------------------------------------------------------------------------
__global__ __launch_bounds__(256) void in_stats_nhwc_k(const short* __restrict__ x,
                                                       float* __restrict__ sums,
                                                       int C, int lC)
{
    __shared__ float ls[256], lss[256];
    const int tid = threadIdx.x;
    const int b = blockIdx.y;
    const int c = tid & (C - 1);
    const int sub = tid >> lC;
    const int tpc = 256 >> lC;
    const int px0 = blockIdx.x * 512;
    float s = 0.f, ss = 0.f;
    for (int p = sub; p < 512; p += tpc) {
        float v = s2f(x[(size_t)(b * 65536 + px0 + p) * C + c]);
        s += v; ss += v * v;
    }
    ls[tid] = s; lss[tid] = ss;
    __syncthreads();
    if (tid < C) {
        float s0 = ls[tid], ss0 = lss[tid];
        for (int j = 1; j < tpc; ++j) { s0 += ls[tid + j * C]; ss0 += lss[tid + j * C]; }
        atomicAdd(sums + 2 * (b * C + tid), s0);
        atomicAdd(sums + 2 * (b * C + tid) + 1, ss0);
    }
}

__global__ __launch_bounds__(256) void in_finalize_k(const float* __restrict__ sums,
                                                     float* __restrict__ stats, int n)
{
    int i = blockIdx.x * 256 + threadIdx.x;
    if (i >= n) return;
    float m = sums[2 * i] * (1.f / 65536.f);
    float var = sums[2 * i + 1] * (1.f / 65536.f) - m * m;
    if (var < 0.f) var = 0.f;
    stats[2 * i] = m;
    stats[2 * i + 1] = rsqrtf(var + 1e-5f);
}

__global__ __launch_bounds__(256) void in_apply_nhwc_k(short* __restrict__ x,
                                                       const float* __restrict__ stats,
                                                       const float* __restrict__ gamma,
                                                       const float* __restrict__ beta,
                                                       int C, int lC, int n4)
{
    int i = blockIdx.x * 256 + threadIdx.x;
    if (i >= n4) return;
    int e0 = i * 4;
    int c0 = e0 & (C - 1);
    int b = e0 >> (16 + lC);
    ushort4 u = reinterpret_cast<ushort4*>(x)[i];
    unsigned short vs[4] = {u.x, u.y, u.z, u.w};
    #pragma unroll
    for (int j = 0; j < 4; ++j) {
        int bc = b * C + c0 + j;
        float t = (s2f((short)vs[j]) - stats[2 * bc]) * stats[2 * bc + 1]
                  * gamma[c0 + j] + beta[c0 + j];
        vs[j] = (unsigned short)f2s(t >= 0.f ? t : 0.2f * t);
    }
    u.x = vs[0]; u.y = vs[1]; u.z = vs[2]; u.w = vs[3];
    reinterpret_cast<ushort4*>(x)[i] = u;
}

// ---------------------------------------------------------------------------
// Separable 7x7 gaussian blur of f1 (A ch 0-63, replicate edges) -> fp16
// planes, group-major: B1[((g*4+b)<<16 | px)*8 + c].  One (16x16 tile,
// 8-ch group) per block; grid (256*8, B), block 256. LDS 24.6 KB, 2 barriers.
// ---------------------------------------------------------------------------
__global__ __launch_bounds__(256) void blur_k(const short* __restrict__ A,
                                              short* __restrict__ B1)
{
    __shared__ __align__(16) short raw[484 * 8];    // 22x22 halo, 7.7 KB
    __shared__ __align__(16) float hb[352 * 12];    // 22 rows x 16 cols, 16.9 KB

    const int tid  = threadIdx.x;
    const int tile = blockIdx.x >> 3;
    const int g    = blockIdx.x & 7;
    const int c0   = g * 8;
    const int tx = (tile & 15) << 4;
    const int ty = (tile >> 4) << 4;
    const int b  = blockIdx.y;

    #pragma unroll
    for (int it = 0; it < 2; ++it) {
        int i = tid + it * 256;
        if (i < 484) {
            int y = i / 22, x = i - y * 22;
            int gy = ty + y - 3, gx = tx + x - 3;
            gy = gy < 0 ? 0 : (gy > 255 ? 255 : gy);
            gx = gx < 0 ? 0 : (gx > 255 ? 255 : gx);
            *reinterpret_cast<short8*>(&raw[i * 8]) =
                *reinterpret_cast<const short8*>(
                    &A[(size_t)((b << 16) + (gy << 8) + gx) * 128 + c0]);
        }
    }
    __syncthreads();

    #pragma unroll
    for (int it = 0; it < 2; ++it) {
        int i = tid + it * 256;
        if (i < 352) {                       // 22 rows x 16 core cols
            int r = i >> 4, cc = i & 15;
            float s[8];
            #pragma unroll
            for (int c = 0; c < 8; ++c) s[c] = 0.f;
            #pragma unroll
            for (int j = 0; j < 7; ++j) {
                short8 v = *reinterpret_cast<const short8*>(&raw[(r * 22 + cc + j) * 8]);
                float w = gw(j);
                #pragma unroll
                for (int c = 0; c < 8; ++c) s[c] += w * s2f(v[c]);
            }
            #pragma unroll
            for (int c = 0; c < 8; ++c) hb[i * 12 + c] = s[c];
        }
    }
    __syncthreads();

    const int py = tid >> 4, px = tid & 15;
    float s[8];
    #pragma unroll
    for (int c = 0; c < 8; ++c) s[c] = 0.f;
    #pragma unroll
    for (int j = 0; j < 7; ++j) {
        const float* hp = &hb[((py + j) * 16 + px) * 12];
        float w = gw(j);
        #pragma unroll
        for (int c = 0; c < 8; ++c) s[c] += w * hp[c];
    }
    short8 ov;
    #pragma unroll
    for (int c = 0; c < 8; ++c) ov[c] = f2h(s[c]);
    *reinterpret_cast<short8*>(
        &B1[(size_t)(((g * 4 + b) << 16) + ((ty + py) << 8) + tx + px) * 8]) = ov;
}

// ---------------------------------------------------------------------------
// Local correlation from pre-blurred f1 (fp16 planes) + f2 (A ch 64-127).
// Per 8-ch group: stage 22x22 blurred tile (zero outside image) into padded
// LDS (stride 12 floats), accumulate 49 SSDs. LDS 23.2 KB, 16 barriers.
// Block 256 = 16x16 px. Grid (256, B).  NO second launch_bounds arg (R8's
// (256,4) capped VGPR at 64 -> acc[49] spilled -> 4.4 GB scratch traffic).
// ---------------------------------------------------------------------------
__global__ __launch_bounds__(256) void corr2_k(const short* __restrict__ A,
                                               const short* __restrict__ B1,
                                               short* __restrict__ lcPad,
                                               float* __restrict__ lcsum)
{
    __shared__ __align__(16) float bl[484 * 12];    // 23.2 KB
    __shared__ float red[4];

    const int tid = threadIdx.x;
    const int tx = (blockIdx.x & 15) << 4;
    const int ty = (blockIdx.x >> 4) << 4;
    const int b  = blockIdx.y;
    const int py = tid >> 4, px = tid & 15;

    float acc[49];
    #pragma unroll
    for (int k = 0; k < 49; ++k) acc[k] = 0.f;

    for (int g = 0; g < 8; ++g) {
        const int c0 = g * 8;
        const size_t plane = (size_t)(g * 4 + b) << 16;

        #pragma unroll
        for (int it = 0; it < 2; ++it) {
            int i = tid + it * 256;
            if (i < 484) {
                int y = i / 22, x = i - y * 22;
                int gy = ty + y - 3, gx = tx + x - 3;
                bool okp = (gy >= 0 && gy < 256 && gx >= 0 && gx < 256);
                f32x4 lo = {0.f, 0.f, 0.f, 0.f};
                f32x4 hi = {0.f, 0.f, 0.f, 0.f};
                if (okp) {
                    short8 v = *reinterpret_cast<const short8*>(
                        &B1[(plane + (gy << 8) + gx) * 8]);
                    lo.x = h2f(v[0]); lo.y = h2f(v[1]);
                    lo.z = h2f(v[2]); lo.w = h2f(v[3]);
                    hi.x = h2f(v[4]); hi.y = h2f(v[5]);
                    hi.z = h2f(v[6]); hi.w = h2f(v[7]);
                }
                *reinterpret_cast<f32x4*>(&bl[i * 12])     = lo;
                *reinterpret_cast<f32x4*>(&bl[i * 12 + 4]) = hi;
            }
        }
        __syncthreads();

        short8 f2v = *reinterpret_cast<const short8*>(
            &A[(size_t)((b << 16) + ((ty + py) << 8) + tx + px) * 128 + 64 + c0]);
        float f2f[8];
        #pragma unroll
        for (int c = 0; c < 8; ++c) f2f[c] = s2f(f2v[c]);

        const float* blp = &bl[(py * 22 + px) * 12];
        #pragma unroll
        for (int i = 0; i < 7; ++i)
            #pragma unroll
            for (int j = 0; j < 7; ++j) {
                const float* cell = blp + (i * 22 + j) * 12;
                f32x4 lo = *reinterpret_cast<const f32x4*>(cell);
                f32x4 hi = *reinterpret_cast<const f32x4*>(cell + 4);
                float a = acc[i * 7 + j];
                float d;
                d = f2f[0] - lo.x; a += d * d;
                d = f2f[1] - lo.y; a += d * d;
                d = f2f[2] - lo.z; a += d * d;
                d = f2f[3] - lo.w; a += d * d;
                d = f2f[4] - hi.x; a += d * d;
                d = f2f[5] - hi.y; a += d * d;
                d = f2f[6] - hi.z; a += d * d;
                d = f2f[7] - hi.w; a += d * d;
                acc[i * 7 + j] = a;
            }
        __syncthreads();
    }

    const size_t base = (size_t)((b << 16) + ((ty + py) << 8) + tx + px) * 64;
    float tot = 0.f;
    #pragma unroll
    for (int k = 0; k < 49; ++k) {
        float m = acc[k] * (1.f / 64.f);
        lcPad[base + k] = f2s(m);
        tot += m;
    }
    #pragma unroll
    for (int k = 49; k < 64; ++k) lcPad[base + k] = 0;

    for (int o = 32; o; o >>= 1) tot += __shfl_down(tot, o);
    if ((tid & 63) == 0) red[tid >> 6] = tot;
    __syncthreads();
    if (tid == 0) atomicAdd(lcsum + b, red[0] + red[1] + red[2] + red[3]);
}

__global__ __launch_bounds__(256) void lc_norm_k(short* __restrict__ lc,
                                                 const float* __restrict__ ls, int n4)
{
    int i = blockIdx.x * 256 + threadIdx.x;
    if (i >= n4) return;
    int b = (i * 4) >> 22;
    float sc = 1.f / (ls[b] * (1.f / 3211264.f) + 1e-6f);
    ushort4 u = reinterpret_cast<ushort4*>(lc)[i];
    u.x = (unsigned short)f2s(s2f((short)u.x) * sc);
    u.y = (unsigned short)f2s(s2f((short)u.y) * sc);
    u.z = (unsigned short)f2s(s2f((short)u.z) * sc);
    u.w = (unsigned short)f2s(s2f((short)u.w) * sc);
    reinterpret_cast<ushort4*>(lc)[i] = u;
}

// ---------------------------------------------------------------------------
// Head conv: NHWC bf16 [b,px,16] -> NCHW fp32 planes [b*2+oc][px].
// ---------------------------------------------------------------------------
__global__ __launch_bounds__(256) void head_k(const short* __restrict__ e3,
                                              const float* __restrict__ w,
                                              const float* __restrict__ bias,
                                              float* __restrict__ hd)
{
    int pix = blockIdx.x * 256 + threadIdx.x;
    int b = pix >> 16, rem = pix & 65535;
    int y = rem >> 8, x = rem & 255;
    float a0 = bias[0], a1 = bias[1];
    #pragma unroll
    for (int tap = 0; tap < 9; ++tap) {
        int yy = y + tap / 3 - 1, xx = x + tap % 3 - 1;
        if ((unsigned)yy >= 256u || (unsigned)xx >= 256u) continue;
        const short* p = e3 + (size_t)((b << 16) + (yy << 8) + xx) * 16;
        #pragma unroll
        for (int ic = 0; ic < 16; ++ic) {
            float v = s2f(p[ic]);
            a0 += v * w[ic * 9 + tap];
            a1 += v * w[(16 + ic) * 9 + tap];
        }
    }
    hd[(size_t)(b * 2) * 65536 + rem]     = a0;
    hd[(size_t)(b * 2 + 1) * 65536 + rem] = a1;
}

// ---------------------------------------------------------------------------
// Final separable 7-tap gaussian blur (replicate edges), fp32 planes.
// ---------------------------------------------------------------------------
__global__ __launch_bounds__(256) void blur7f_k(const float* __restrict__ in,
                                                float* __restrict__ out)
{
    __shared__ float raw[22 * 22];
    __shared__ float hb[22 * 16];
    const int tid = threadIdx.x;
    const int tx = (blockIdx.x & 15) << 4;
    const int ty = (blockIdx.x >> 4) << 4;
    const size_t ch = ((size_t)blockIdx.y) << 16;
    const int py = tid >> 4, px = tid & 15;

    for (int i = tid; i < 484; i += 256) {
        int y = i / 22, x = i - y * 22;
        int gy = ty + y - 3, gx = tx + x - 3;
        gy = gy < 0 ? 0 : (gy > 255 ? 255 : gy);
        gx = gx < 0 ? 0 : (gx > 255 ? 255 : gx);
        raw[i] = in[ch + (gy << 8) + gx];
    }
    __syncthreads();
    for (int i = tid; i < 352; i += 256) {
        int r = i >> 4, cc = i & 15;
        float s = 0.f;
        #pragma unroll
        for (int j = 0; j < 7; ++j) s += gw(j) * raw[r * 22 + cc + j];
        hb[i] = s;
    }
    __syncthreads();
    float s = 0.f;
    #pragma unroll
    for (int j = 0; j < 7; ++j) s += gw(j) * hb[(py + j) * 16 + px];
    out[ch + ((ty + py) << 8) + tx + px] = s;
}

// ---------------------------------------------------------------------------
extern "C" void kernel_launch(void* const* d_in, const int* in_sizes, int n_in,
                              void* d_out, int out_size, void* d_ws, size_t ws_size,
                              hipStream_t stream)
{
    const float* feat1  = (const float*)d_in[0];
    const float* feat2  = (const float*)d_in[1];
    const float* pre_w  = (const float*)d_in[2];
    const float* pre_b  = (const float*)d_in[3];
    const float* fc1_w  = (const float*)d_in[4];
    const float* fc1_g  = (const float*)d_in[5];
    const float* fc1_be = (const float*)d_in[6];
    const float* fc2_w  = (const float*)d_in[7];
    const float* fc2_b  = (const float*)d_in[8];
    const float* e1_w   = (const float*)d_in[9];
    const float* e1_g   = (const float*)d_in[10];
    const float* e1_be  = (const float*)d_in[11];
    const float* e2_w   = (const float*)d_in[12];
    const float* e2_g   = (const float*)d_in[13];
    const float* e2_be  = (const float*)d_in[14];
    const float* e3_w   = (const float*)d_in[15];
    const float* e3_g   = (const float*)d_in[16];
    const float* e3_be  = (const float*)d_in[17];
    const float* head_w = (const float*)d_in[18];
    const float* head_b = (const float*)d_in[19];
    float* out = (float*)d_out;

    const size_t NEED = 152000000;
    if (ws_size < NEED) return;

    char* ws = (char*)d_ws;
    short* T1      = (short*)(ws);
    short* T2      = (short*)(ws + 33554432);
    short* lcPad   = (short*)(ws);
    short* B1h     = (short*)(ws + 33554432);   // blurred f1, fp16 group-major
    short* featBuf = (short*)(ws + 33554432);
    short* A       = (short*)(ws + 67108864);
    short* FC1o    = (short*)(ws + 83886080);
    short* E1o     = (short*)(ws + 67108864);
    short* E2o     = (short*)(ws + 100663296);
    short* E3o     = (short*)(ws + 117440512);
    float* HD      = (float*)(ws + 125829120);
    short* preW    = (short*)(ws + 150994944);
    short* fc1W    = (short*)(ws + 151068672);
    short* fc2W    = (short*)(ws + 151363584);
    short* e1W     = (short*)(ws + 151511040);
    short* e2W     = (short*)(ws + 151658496);
    short* e3W     = (short*)(ws + 151695360);
    float* sums0   = (float*)(ws + 151704576);
    float* sums1   = (float*)(ws + 151708672);
    float* sums2   = (float*)(ws + 151712768);
    float* sums3   = (float*)(ws + 151716864);
    float* stats0  = (float*)(ws + 151720960);
    float* stats1  = (float*)(ws + 151725056);
    float* stats2  = (float*)(ws + 151729152);
    float* stats3  = (float*)(ws + 151733248);
    float* LS      = (float*)(ws + 151737344);

    hipMemsetAsync(ws + 151704576, 0, 32784, stream);

    transpose_k<<<dim3(1024, 4), 256, 0, stream>>>(feat1, T1);
    transpose_k<<<dim3(1024, 4), 256, 0, stream>>>(feat2, T2);

    repack2_k<<<144, 256, 0, stream>>>(pre_w, preW, 64, 64, 64);
    repack2_k<<<576, 256, 0, stream>>>(fc1_w, fc1W, 128, 128, 128);
    repack2_k<<<288, 256, 0, stream>>>(fc2_w, fc2W, 64, 128, 128);
    repack2_k<<<288, 256, 0, stream>>>(e1_w, e1W, 64, 113, 128);
    repack2_k<<<72, 256, 0, stream>>>(e2_w, e2W, 32, 64, 64);
    repack2_k<<<18, 256, 0, stream>>>(e3_w, e3W, 16, 32, 32);

    // pre conv (cout=64): G=4, NOC=4, WY=1 -> block 256px x 64oc
    convmfma_k<1, 64, 1, 4, 4><<<dim3(256, 1, 4), 256, 0, stream>>>(
        T1, T1, 64, 64, 64, preW, pre_b, A, 128, 0, 0);
    convmfma_k<1, 64, 1, 4, 4><<<dim3(256, 1, 4), 256, 0, stream>>>(
        T2, T2, 64, 64, 64, preW, pre_b, A, 128, 64, 0);

    // blur f1 -> fp16 planes, then local correlation + normalize
    blur_k<<<dim3(2048, 4), 256, 0, stream>>>(A, B1h);
    corr2_k<<<dim3(256, 4), 256, 0, stream>>>(A, B1h, lcPad, LS);
    lc_norm_k<<<16384, 256, 0, stream>>>(lcPad, LS, 4194304);

    // fc1 (cout=128): G=4, NOC=4, WY=2 -> block 128px x 128oc; batch-phased
    for (int b = 3; b >= 0; --b)
        convmfma_k<1, 128, 2, 4, 4><<<dim3(512, 1, 1), 256, 0, stream>>>(
            A, A, 128, 128, 128, fc1W, nullptr, FC1o, 128, 0, b);
    in_stats_nhwc_k<<<dim3(128, 4), 256, 0, stream>>>(FC1o, sums0, 128, 7);
    in_finalize_k<<<2, 256, 0, stream>>>(sums0, stats0, 512);
    in_apply_nhwc_k<<<32768, 256, 0, stream>>>(FC1o, stats0, fc1_g, fc1_be, 128, 7, 8388608);

    // fc2 (cout=64): G=4, NOC=4, WY=1
    convmfma_k<1, 128, 1, 4, 4><<<dim3(256, 1, 4), 256, 0, stream>>>(
        FC1o, FC1o, 128, 128, 128, fc2W, fc2_b, featBuf, 64, 0, 0);

    // e1 (cout=64): concat(featBuf, lcPad)
    convmfma_k<1, 128, 1, 4, 4><<<dim3(256, 1, 4), 256, 0, stream>>>(
        featBuf, lcPad, 64, 64, 64, e1W, nullptr, E1o, 64, 0, 0);
    in_stats_nhwc_k<<<dim3(128, 4), 256, 0, stream>>>(E1o, sums1, 64, 6);
    in_finalize_k<<<1, 256, 0, stream>>>(sums1, stats1, 256);
    in_apply_nhwc_k<<<16384, 256, 0, stream>>>(E1o, stats1, e1_g, e1_be, 64, 6, 4194304);

    // e2 (cout=32): dil=2, G=4, NOC=2
    convmfma_k<2, 64, 1, 2, 4><<<dim3(256, 1, 4), 256, 0, stream>>>(
        E1o, E1o, 64, 64, 64, e2W, nullptr, E2o, 32, 0, 0);
    in_stats_nhwc_k<<<dim3(128, 4), 256, 0, stream>>>(E2o, sums2, 32, 5);
    in_finalize_k<<<1, 256, 0, stream>>>(sums2, stats2, 128);
    in_apply_nhwc_k<<<8192, 256, 0, stream>>>(E2o, stats2, e2_g, e2_be, 32, 5, 2097152);

    // e3 (cout=16): dil=4, G=4, NOC=1
    convmfma_k<4, 32, 1, 1, 4><<<dim3(256, 1, 4), 256, 0, stream>>>(
        E2o, E2o, 32, 32, 32, e3W, nullptr, E3o, 16, 0, 0);
    in_stats_nhwc_k<<<dim3(128, 4), 256, 0, stream>>>(E3o, sums3, 16, 4);
    in_finalize_k<<<1, 256, 0, stream>>>(sums3, stats3, 64);
    in_apply_nhwc_k<<<4096, 256, 0, stream>>>(E3o, stats3, e3_g, e3_be, 16, 4, 1048576);

    head_k<<<1024, 256, 0, stream>>>(E3o, head_w, head_b, HD);
    blur7f_k<<<dim3(256, 8), 256, 0, stream>>>(HD, out);
}

// Round 3
// 1234.089 us; speedup vs baseline: 2.1044x; 1.0666x over previous
//
#include <hip/hip_runtime.h>
#include <hip/hip_bf16.h>

// ---------------------------------------------------------------------------
// DispEstimator pipeline, MFMA bf16 implicit-GEMM (R10).
// R10: corr2_k reworked to fp16 LDS payload + v_dot2_f32_f16 SSD:
//  - blurred tile staged as raw fp16 (16B/cell, 1x ds_read_b128 per cell,
//    was 2x fp32) -> LDS 15.5KB double-buffered, 8 barriers (was 16)
//  - per-cell VALU: 4x v_pk_add_f16 + 4x v_dot2_f32_f16 (was 8 sub + 8 fma)
//  - __launch_bounds__(256,2): empirical mapping (R8: arg4 -> cap 64) gives
//    cap 128 -> 4 blocks/CU (R9's unbounded alloc hit 236 VGPR, 2 blocks/CU).
// ---------------------------------------------------------------------------

typedef __attribute__((ext_vector_type(8))) short short8;
typedef __attribute__((ext_vector_type(4))) float f32x4;
typedef _Float16 f16x8 __attribute__((ext_vector_type(8)));
typedef _Float16 f16x2 __attribute__((ext_vector_type(2)));

__device__ __forceinline__ float s2f(short s) {
    unsigned int u = ((unsigned int)(unsigned short)s) << 16;
    float f; __builtin_memcpy(&f, &u, 4); return f;
}
__device__ __forceinline__ short f2s(float f) {
    __hip_bfloat16 h = __float2bfloat16(f);
    short s; __builtin_memcpy(&s, &h, 2); return s;
}
__device__ __forceinline__ float h2f(short s) {
    _Float16 h; __builtin_memcpy(&h, &s, 2); return (float)h;
}
__device__ __forceinline__ short f2h(float f) {
    _Float16 h = (_Float16)f;
    short s; __builtin_memcpy(&s, &h, 2); return s;
}

__device__ __forceinline__ float gw(int j) {
    const float G[7] = {0.0366329f, 0.1112808f, 0.2167453f, 0.2706821f,
                        0.2167453f, 0.1112808f, 0.0366329f};
    return G[j];
}

// ---------------------------------------------------------------------------
// NCHW fp32 -> NHWC bf16 transpose. grid (1024, B), block 256.
// ---------------------------------------------------------------------------
__global__ __launch_bounds__(256) void transpose_k(const float* __restrict__ in,
                                                   short* __restrict__ out)
{
    __shared__ float t[64][65];
    const int b = blockIdx.y;
    const int px0 = blockIdx.x * 64;
    #pragma unroll
    for (int k = 0; k < 16; ++k) {
        int idx = threadIdx.x + k * 256;
        int c = idx >> 6, x = idx & 63;
        t[c][x] = in[(size_t)(b * 64 + c) * 65536 + px0 + x];
    }
    __syncthreads();
    #pragma unroll
    for (int k = 0; k < 16; ++k) {
        int idx = threadIdx.x + k * 256;
        int px = idx >> 6, c = idx & 63;
        out[(size_t)(b * 65536 + px0 + px) * 64 + c] = f2s(t[c][px]);
    }
}

// ---------------------------------------------------------------------------
// Weight repack v2: [oc][cin][3][3] fp32 -> MFMA-native
// [o16][tap][cb][lane][8] bf16 (o16 = oc/16, cb = k-block of 32, lane=q*16+n16;
// element (lane,c8) <-> oc = o16*16+n16, ic = cb*32+q*8+c8). Zero-padded.
// ---------------------------------------------------------------------------
__global__ __launch_bounds__(256) void repack2_k(const float* __restrict__ w,
                                                 short* __restrict__ o,
                                                 int cout, int cin, int CINP)
{
    int idx = blockIdx.x * 256 + threadIdx.x;
    int CB = CINP >> 5;
    int tot = cout * 9 * CINP;
    if (idx >= tot) return;
    int c8   = idx & 7;
    int lane = (idx >> 3) & 63;
    int rest = idx >> 9;          // ((o16*9+tap)*CB + cb)
    int cb   = rest % CB;
    int rest2 = rest / CB;
    int tap  = rest2 % 9;
    int o16  = rest2 / 9;
    int n16 = lane & 15, q = lane >> 4;
    int oc = o16 * 16 + n16;
    int ic = cb * 32 + q * 8 + c8;
    float v = (ic < cin) ? w[(size_t)(oc * cin + ic) * 9 + tap] : 0.f;
    o[idx] = f2s(v);
}

// ---------------------------------------------------------------------------
// MFMA implicit-GEMM 3x3 conv, NHWC bf16, zero pad = DIL.
// Wave: G*16 px x 16*NOC oc. Block 4 waves (WX px-groups x WY oc-groups).
// Weights in MFMA-native layout (repack2_k). grid:(XT*256, cout/(16*NOC*WY), nb)
// ---------------------------------------------------------------------------
template<int DIL, int CINP, int WY, int NOC, int G>
__global__ __launch_bounds__(256) void convmfma_k(
    const short* __restrict__ srcA, const short* __restrict__ srcB,
    int splitK, int csA, int csB,
    const short* __restrict__ wgt, const float* __restrict__ bias,
    short* __restrict__ out, int OSTR, int OBASE, int b0)
{
    constexpr int WX  = 4 / WY;
    constexpr int PXW = G * 16;
    constexpr int PXB = PXW * WX;
    constexpr int XT  = 256 / PXB;
    constexpr int CB  = CINP / 32;

    const int lane = threadIdx.x & 63;
    const int wave = threadIdx.x >> 6;
    const int q = lane >> 4, n16 = lane & 15;
    const int wx = wave % WX, wy = wave / WX;
    const int xt = blockIdx.x % XT;
    const int y  = blockIdx.x / XT;
    const int b  = b0 + blockIdx.z;
    const int ocWaveBase = blockIdx.y * (16 * NOC * WY) + wy * (16 * NOC);
    const int o16base = ocWaveBase >> 4;
    const int x0 = xt * PXB + wx * PXW;

    f32x4 acc[G][NOC];
    #pragma unroll
    for (int g = 0; g < G; ++g)
        #pragma unroll
        for (int t = 0; t < NOC; ++t)
            acc[g][t] = {0.f, 0.f, 0.f, 0.f};

    #pragma unroll
    for (int tap = 0; tap < 9; ++tap) {
        const int dy = (tap / 3 - 1) * DIL;
        const int dx = (tap % 3 - 1) * DIL;
        const int yy = y + dy;
        const bool rowok = ((unsigned)yy < 256u);
        const int yyc = rowok ? yy : (yy < 0 ? 0 : 255);
        const int rowbase = (b * 256 + yyc) * 256;
        bool ok[G]; int xc[G];
        #pragma unroll
        for (int g = 0; g < G; ++g) {
            int xx = x0 + g * 16 + n16 + dx;
            bool xok = ((unsigned)xx < 256u);
            ok[g] = rowok && xok;
            xc[g] = xok ? xx : (xx < 0 ? 0 : 255);
        }
        #pragma unroll
        for (int cb = 0; cb < CB; ++cb) {
            const int icb = cb * 32;
            const int ic = icb + q * 8;
            const short* sp; int icc, cs;
            if (icb < splitK) { sp = srcA; icc = ic; cs = csA; }
            else              { sp = srcB; icc = ic - splitK; cs = csB; }
            short8 bfr[G];
            #pragma unroll
            for (int g = 0; g < G; ++g) {
                short8 v = *reinterpret_cast<const short8*>(
                    sp + (size_t)(rowbase + xc[g]) * cs + icc);
                if (!ok[g]) v = v ^ v;
                bfr[g] = v;
            }
            #pragma unroll
            for (int t = 0; t < NOC; ++t) {
                short8 a = *reinterpret_cast<const short8*>(
                    wgt + ((((size_t)(o16base + t) * 9 + tap) * CB + cb) * 64 + lane) * 8);
                #pragma unroll
                for (int g = 0; g < G; ++g)
                    acc[g][t] = __builtin_amdgcn_mfma_f32_16x16x32_bf16(
                        a, bfr[g], acc[g][t], 0, 0, 0);
            }
        }
    }

    #pragma unroll
    for (int g = 0; g < G; ++g) {
        const size_t px_lin = (size_t)(b * 256 + y) * 256 + x0 + g * 16 + n16;
        #pragma unroll
        for (int t = 0; t < NOC; ++t) {
            const int oc = ocWaveBase + t * 16 + q * 4;
            f32x4 v = acc[g][t];
            if (bias) {
                v.x += bias[oc];     v.y += bias[oc + 1];
                v.z += bias[oc + 2]; v.w += bias[oc + 3];
            }
            ushort4 pk;
            pk.x = (unsigned short)f2s(v.x);
            pk.y = (unsigned short)f2s(v.y);
            pk.z = (unsigned short)f2s(v.z);
            pk.w = (unsigned short)f2s(v.w);
            *reinterpret_cast<ushort4*>(out + px_lin * OSTR + OBASE + oc) = pk;
        }
    }
}

// ---------------------------------------------------------------------------
// Instance-norm partial sums, NHWC. grid (128 slices, B), block 256.
// ---------------------------------------------------------------------------
__global__ __launch_bounds__(256) void in_stats_nhwc_k(const short* __restrict__ x,
                                                       float* __restrict__ sums,
                                                       int C, int lC)
{
    __shared__ float ls[256], lss[256];
    const int tid = threadIdx.x;
    const int b = blockIdx.y;
    const int c = tid & (C - 1);
    const int sub = tid >> lC;
    const int tpc = 256 >> lC;
    const int px0 = blockIdx.x * 512;
    float s = 0.f, ss = 0.f;
    for (int p = sub; p < 512; p += tpc) {
        float v = s2f(x[(size_t)(b * 65536 + px0 + p) * C + c]);
        s += v; ss += v * v;
    }
    ls[tid] = s; lss[tid] = ss;
    __syncthreads();
    if (tid < C) {
        float s0 = ls[tid], ss0 = lss[tid];
        for (int j = 1; j < tpc; ++j) { s0 += ls[tid + j * C]; ss0 += lss[tid + j * C]; }
        atomicAdd(sums + 2 * (b * C + tid), s0);
        atomicAdd(sums + 2 * (b * C + tid) + 1, ss0);
    }
}

__global__ __launch_bounds__(256) void in_finalize_k(const float* __restrict__ sums,
                                                     float* __restrict__ stats, int n)
{
    int i = blockIdx.x * 256 + threadIdx.x;
    if (i >= n) return;
    float m = sums[2 * i] * (1.f / 65536.f);
    float var = sums[2 * i + 1] * (1.f / 65536.f) - m * m;
    if (var < 0.f) var = 0.f;
    stats[2 * i] = m;
    stats[2 * i + 1] = rsqrtf(var + 1e-5f);
}

__global__ __launch_bounds__(256) void in_apply_nhwc_k(short* __restrict__ x,
                                                       const float* __restrict__ stats,
                                                       const float* __restrict__ gamma,
                                                       const float* __restrict__ beta,
                                                       int C, int lC, int n4)
{
    int i = blockIdx.x * 256 + threadIdx.x;
    if (i >= n4) return;
    int e0 = i * 4;
    int c0 = e0 & (C - 1);
    int b = e0 >> (16 + lC);
    ushort4 u = reinterpret_cast<ushort4*>(x)[i];
    unsigned short vs[4] = {u.x, u.y, u.z, u.w};
    #pragma unroll
    for (int j = 0; j < 4; ++j) {
        int bc = b * C + c0 + j;
        float t = (s2f((short)vs[j]) - stats[2 * bc]) * stats[2 * bc + 1]
                  * gamma[c0 + j] + beta[c0 + j];
        vs[j] = (unsigned short)f2s(t >= 0.f ? t : 0.2f * t);
    }
    u.x = vs[0]; u.y = vs[1]; u.z = vs[2]; u.w = vs[3];
    reinterpret_cast<ushort4*>(x)[i] = u;
}

// ---------------------------------------------------------------------------
// Separable 7x7 gaussian blur of f1 (A ch 0-63, replicate edges) -> fp16
// planes, group-major: B1[((g*4+b)<<16 | px)*8 + c].  One (16x16 tile,
// 8-ch group) per block; grid (256*8, B), block 256. LDS 24.6 KB, 2 barriers.
// ---------------------------------------------------------------------------
__global__ __launch_bounds__(256) void blur_k(const short* __restrict__ A,
                                              short* __restrict__ B1)
{
    __shared__ __align__(16) short raw[484 * 8];    // 22x22 halo, 7.7 KB
    __shared__ __align__(16) float hb[352 * 12];    // 22 rows x 16 cols, 16.9 KB

    const int tid  = threadIdx.x;
    const int tile = blockIdx.x >> 3;
    const int g    = blockIdx.x & 7;
    const int c0   = g * 8;
    const int tx = (tile & 15) << 4;
    const int ty = (tile >> 4) << 4;
    const int b  = blockIdx.y;

    #pragma unroll
    for (int it = 0; it < 2; ++it) {
        int i = tid + it * 256;
        if (i < 484) {
            int y = i / 22, x = i - y * 22;
            int gy = ty + y - 3, gx = tx + x - 3;
            gy = gy < 0 ? 0 : (gy > 255 ? 255 : gy);
            gx = gx < 0 ? 0 : (gx > 255 ? 255 : gx);
            *reinterpret_cast<short8*>(&raw[i * 8]) =
                *reinterpret_cast<const short8*>(
                    &A[(size_t)((b << 16) + (gy << 8) + gx) * 128 + c0]);
        }
    }
    __syncthreads();

    #pragma unroll
    for (int it = 0; it < 2; ++it) {
        int i = tid + it * 256;
        if (i < 352) {                       // 22 rows x 16 core cols
            int r = i >> 4, cc = i & 15;
            float s[8];
            #pragma unroll
            for (int c = 0; c < 8; ++c) s[c] = 0.f;
            #pragma unroll
            for (int j = 0; j < 7; ++j) {
                short8 v = *reinterpret_cast<const short8*>(&raw[(r * 22 + cc + j) * 8]);
                float w = gw(j);
                #pragma unroll
                for (int c = 0; c < 8; ++c) s[c] += w * s2f(v[c]);
            }
            #pragma unroll
            for (int c = 0; c < 8; ++c) hb[i * 12 + c] = s[c];
        }
    }
    __syncthreads();

    const int py = tid >> 4, px = tid & 15;
    float s[8];
    #pragma unroll
    for (int c = 0; c < 8; ++c) s[c] = 0.f;
    #pragma unroll
    for (int j = 0; j < 7; ++j) {
        const float* hp = &hb[((py + j) * 16 + px) * 12];
        float w = gw(j);
        #pragma unroll
        for (int c = 0; c < 8; ++c) s[c] += w * hp[c];
    }
    short8 ov;
    #pragma unroll
    for (int c = 0; c < 8; ++c) ov[c] = f2h(s[c]);
    *reinterpret_cast<short8*>(
        &B1[(size_t)(((g * 4 + b) << 16) + ((ty + py) << 8) + tx + px) * 8]) = ov;
}

// ---------------------------------------------------------------------------
// Local correlation from pre-blurred f1 (fp16 planes) + f2 (A ch 64-127).
// Per 8-ch group: stage 22x22 fp16 tile (16B/cell) into double-buffered LDS,
// SSD via v_pk_add_f16 + v_dot2_f32_f16 (f32 accum). 1 ds_read_b128/cell,
// 8 barriers. LDS 15.5KB. Block 256 = 16x16 px. Grid (256, B).
// ---------------------------------------------------------------------------
__global__ __launch_bounds__(256, 2) void corr2_k(const short* __restrict__ A,
                                                  const short* __restrict__ B1,
                                                  short* __restrict__ lcPad,
                                                  float* __restrict__ lcsum)
{
    __shared__ __align__(16) short blh[2][484 * 8];  // fp16 payload, 15.5 KB
    __shared__ float red[4];

    const int tid = threadIdx.x;
    const int tx = (blockIdx.x & 15) << 4;
    const int ty = (blockIdx.x >> 4) << 4;
    const int b  = blockIdx.y;
    const int py = tid >> 4, px = tid & 15;

    // Precompute staging descriptors for cells tid and tid+256 (halo +-3).
    int y0 = tid / 22, x0c = tid - y0 * 22;
    int gy0 = ty + y0 - 3, gx0 = tx + x0c - 3;
    const bool ok0 = (gy0 >= 0 && gy0 < 256 && gx0 >= 0 && gx0 < 256);
    gy0 = gy0 < 0 ? 0 : (gy0 > 255 ? 255 : gy0);
    gx0 = gx0 < 0 ? 0 : (gx0 > 255 ? 255 : gx0);
    const int off0 = (gy0 << 8) + gx0;

    const int c1 = tid + 256;
    int y1 = c1 / 22, x1c = c1 - y1 * 22;
    int gy1 = ty + y1 - 3, gx1 = tx + x1c - 3;
    const bool ok1 = (gy1 >= 0 && gy1 < 256 && gx1 >= 0 && gx1 < 256);
    gy1 = gy1 < 0 ? 0 : (gy1 > 255 ? 255 : gy1);
    gx1 = gx1 < 0 ? 0 : (gx1 > 255 ? 255 : gx1);
    const int off1 = (gy1 << 8) + gx1;
    const bool has1 = (c1 < 484);

    const short* f2p = &A[(size_t)((b << 16) + ((ty + py) << 8) + tx + px) * 128 + 64];

    float acc[49];
    #pragma unroll
    for (int k = 0; k < 49; ++k) acc[k] = 0.f;

    for (int g = 0; g < 8; ++g) {
        const size_t plane = (size_t)(g * 4 + b) << 16;
        short* buf = blh[g & 1];

        // stage fp16 tile (pure copy, masked to zero outside image)
        {
            short8 v = *reinterpret_cast<const short8*>(&B1[(plane + off0) * 8]);
            if (!ok0) v = v ^ v;
            *reinterpret_cast<short8*>(&buf[tid * 8]) = v;
            if (has1) {
                short8 w = *reinterpret_cast<const short8*>(&B1[(plane + off1) * 8]);
                if (!ok1) w = w ^ w;
                *reinterpret_cast<short8*>(&buf[c1 * 8]) = w;
            }
        }

        // f2 (bf16) -> fp16 registers
        short8 f2raw = *reinterpret_cast<const short8*>(f2p + g * 8);
        f16x8 f2v;
        #pragma unroll
        for (int c = 0; c < 8; ++c) f2v[c] = (_Float16)s2f(f2raw[c]);

        __syncthreads();

        const short* blp = &buf[(py * 22 + px) * 8];
        #pragma unroll
        for (int i = 0; i < 7; ++i)
            #pragma unroll
            for (int j = 0; j < 7; ++j) {
                f16x8 bv = *reinterpret_cast<const f16x8*>(blp + (i * 22 + j) * 8);
                f16x8 d = f2v - bv;
                float a = acc[i * 7 + j];
#if __has_builtin(__builtin_amdgcn_fdot2)
                a = __builtin_amdgcn_fdot2(__builtin_shufflevector(d, d, 0, 1),
                                           __builtin_shufflevector(d, d, 0, 1), a, false);
                a = __builtin_amdgcn_fdot2(__builtin_shufflevector(d, d, 2, 3),
                                           __builtin_shufflevector(d, d, 2, 3), a, false);
                a = __builtin_amdgcn_fdot2(__builtin_shufflevector(d, d, 4, 5),
                                           __builtin_shufflevector(d, d, 4, 5), a, false);
                a = __builtin_amdgcn_fdot2(__builtin_shufflevector(d, d, 6, 7),
                                           __builtin_shufflevector(d, d, 6, 7), a, false);
#else
                #pragma unroll
                for (int c = 0; c < 8; ++c) {
                    float df = (float)d[c];
                    a += df * df;
                }
#endif
                acc[i * 7 + j] = a;
            }
        // no trailing barrier: next g writes the other buffer; the barrier
        // of iteration g+1 orders our reads of buf[g&1] before g+2's writes.
    }

    const size_t base = (size_t)((b << 16) + ((ty + py) << 8) + tx + px) * 64;
    float tot = 0.f;
    #pragma unroll
    for (int k = 0; k < 49; ++k) {
        float m = acc[k] * (1.f / 64.f);
        lcPad[base + k] = f2s(m);
        tot += m;
    }
    #pragma unroll
    for (int k = 49; k < 64; ++k) lcPad[base + k] = 0;

    for (int o = 32; o; o >>= 1) tot += __shfl_down(tot, o);
    if ((tid & 63) == 0) red[tid >> 6] = tot;
    __syncthreads();
    if (tid == 0) atomicAdd(lcsum + b, red[0] + red[1] + red[2] + red[3]);
}

__global__ __launch_bounds__(256) void lc_norm_k(short* __restrict__ lc,
                                                 const float* __restrict__ ls, int n4)
{
    int i = blockIdx.x * 256 + threadIdx.x;
    if (i >= n4) return;
    int b = (i * 4) >> 22;
    float sc = 1.f / (ls[b] * (1.f / 3211264.f) + 1e-6f);
    ushort4 u = reinterpret_cast<ushort4*>(lc)[i];
    u.x = (unsigned short)f2s(s2f((short)u.x) * sc);
    u.y = (unsigned short)f2s(s2f((short)u.y) * sc);
    u.z = (unsigned short)f2s(s2f((short)u.z) * sc);
    u.w = (unsigned short)f2s(s2f((short)u.w) * sc);
    reinterpret_cast<ushort4*>(lc)[i] = u;
}

// ---------------------------------------------------------------------------
// Head conv: NHWC bf16 [b,px,16] -> NCHW fp32 planes [b*2+oc][px].
// ---------------------------------------------------------------------------
__global__ __launch_bounds__(256) void head_k(const short* __restrict__ e3,
                                              const float* __restrict__ w,
                                              const float* __restrict__ bias,
                                              float* __restrict__ hd)
{
    int pix = blockIdx.x * 256 + threadIdx.x;
    int b = pix >> 16, rem = pix & 65535;
    int y = rem >> 8, x = rem & 255;
    float a0 = bias[0], a1 = bias[1];
    #pragma unroll
    for (int tap = 0; tap < 9; ++tap) {
        int yy = y + tap / 3 - 1, xx = x + tap % 3 - 1;
        if ((unsigned)yy >= 256u || (unsigned)xx >= 256u) continue;
        const short* p = e3 + (size_t)((b << 16) + (yy << 8) + xx) * 16;
        #pragma unroll
        for (int ic = 0; ic < 16; ++ic) {
            float v = s2f(p[ic]);
            a0 += v * w[ic * 9 + tap];
            a1 += v * w[(16 + ic) * 9 + tap];
        }
    }
    hd[(size_t)(b * 2) * 65536 + rem]     = a0;
    hd[(size_t)(b * 2 + 1) * 65536 + rem] = a1;
}

// ---------------------------------------------------------------------------
// Final separable 7-tap gaussian blur (replicate edges), fp32 planes.
// ---------------------------------------------------------------------------
__global__ __launch_bounds__(256) void blur7f_k(const float* __restrict__ in,
                                                float* __restrict__ out)
{
    __shared__ float raw[22 * 22];
    __shared__ float hb[22 * 16];
    const int tid = threadIdx.x;
    const int tx = (blockIdx.x & 15) << 4;
    const int ty = (blockIdx.x >> 4) << 4;
    const size_t ch = ((size_t)blockIdx.y) << 16;
    const int py = tid >> 4, px = tid & 15;

    for (int i = tid; i < 484; i += 256) {
        int y = i / 22, x = i - y * 22;
        int gy = ty + y - 3, gx = tx + x - 3;
        gy = gy < 0 ? 0 : (gy > 255 ? 255 : gy);
        gx = gx < 0 ? 0 : (gx > 255 ? 255 : gx);
        raw[i] = in[ch + (gy << 8) + gx];
    }
    __syncthreads();
    for (int i = tid; i < 352; i += 256) {
        int r = i >> 4, cc = i & 15;
        float s = 0.f;
        #pragma unroll
        for (int j = 0; j < 7; ++j) s += gw(j) * raw[r * 22 + cc + j];
        hb[i] = s;
    }
    __syncthreads();
    float s = 0.f;
    #pragma unroll
    for (int j = 0; j < 7; ++j) s += gw(j) * hb[(py + j) * 16 + px];
    out[ch + ((ty + py) << 8) + tx + px] = s;
}

// ---------------------------------------------------------------------------
extern "C" void kernel_launch(void* const* d_in, const int* in_sizes, int n_in,
                              void* d_out, int out_size, void* d_ws, size_t ws_size,
                              hipStream_t stream)
{
    const float* feat1  = (const float*)d_in[0];
    const float* feat2  = (const float*)d_in[1];
    const float* pre_w  = (const float*)d_in[2];
    const float* pre_b  = (const float*)d_in[3];
    const float* fc1_w  = (const float*)d_in[4];
    const float* fc1_g  = (const float*)d_in[5];
    const float* fc1_be = (const float*)d_in[6];
    const float* fc2_w  = (const float*)d_in[7];
    const float* fc2_b  = (const float*)d_in[8];
    const float* e1_w   = (const float*)d_in[9];
    const float* e1_g   = (const float*)d_in[10];
    const float* e1_be  = (const float*)d_in[11];
    const float* e2_w   = (const float*)d_in[12];
    const float* e2_g   = (const float*)d_in[13];
    const float* e2_be  = (const float*)d_in[14];
    const float* e3_w   = (const float*)d_in[15];
    const float* e3_g   = (const float*)d_in[16];
    const float* e3_be  = (const float*)d_in[17];
    const float* head_w = (const float*)d_in[18];
    const float* head_b = (const float*)d_in[19];
    float* out = (float*)d_out;

    const size_t NEED = 152000000;
    if (ws_size < NEED) return;

    char* ws = (char*)d_ws;
    short* T1      = (short*)(ws);
    short* T2      = (short*)(ws + 33554432);
    short* lcPad   = (short*)(ws);
    short* B1h     = (short*)(ws + 33554432);   // blurred f1, fp16 group-major
    short* featBuf = (short*)(ws + 33554432);
    short* A       = (short*)(ws + 67108864);
    short* FC1o    = (short*)(ws + 83886080);
    short* E1o     = (short*)(ws + 67108864);
    short* E2o     = (short*)(ws + 100663296);
    short* E3o     = (short*)(ws + 117440512);
    float* HD      = (float*)(ws + 125829120);
    short* preW    = (short*)(ws + 150994944);
    short* fc1W    = (short*)(ws + 151068672);
    short* fc2W    = (short*)(ws + 151363584);
    short* e1W     = (short*)(ws + 151511040);
    short* e2W     = (short*)(ws + 151658496);
    short* e3W     = (short*)(ws + 151695360);
    float* sums0   = (float*)(ws + 151704576);
    float* sums1   = (float*)(ws + 151708672);
    float* sums2   = (float*)(ws + 151712768);
    float* sums3   = (float*)(ws + 151716864);
    float* stats0  = (float*)(ws + 151720960);
    float* stats1  = (float*)(ws + 151725056);
    float* stats2  = (float*)(ws + 151729152);
    float* stats3  = (float*)(ws + 151733248);
    float* LS      = (float*)(ws + 151737344);

    hipMemsetAsync(ws + 151704576, 0, 32784, stream);

    transpose_k<<<dim3(1024, 4), 256, 0, stream>>>(feat1, T1);
    transpose_k<<<dim3(1024, 4), 256, 0, stream>>>(feat2, T2);

    repack2_k<<<144, 256, 0, stream>>>(pre_w, preW, 64, 64, 64);
    repack2_k<<<576, 256, 0, stream>>>(fc1_w, fc1W, 128, 128, 128);
    repack2_k<<<288, 256, 0, stream>>>(fc2_w, fc2W, 64, 128, 128);
    repack2_k<<<288, 256, 0, stream>>>(e1_w, e1W, 64, 113, 128);
    repack2_k<<<72, 256, 0, stream>>>(e2_w, e2W, 32, 64, 64);
    repack2_k<<<18, 256, 0, stream>>>(e3_w, e3W, 16, 32, 32);

    // pre conv (cout=64): G=4, NOC=4, WY=1 -> block 256px x 64oc
    convmfma_k<1, 64, 1, 4, 4><<<dim3(256, 1, 4), 256, 0, stream>>>(
        T1, T1, 64, 64, 64, preW, pre_b, A, 128, 0, 0);
    convmfma_k<1, 64, 1, 4, 4><<<dim3(256, 1, 4), 256, 0, stream>>>(
        T2, T2, 64, 64, 64, preW, pre_b, A, 128, 64, 0);

    // blur f1 -> fp16 planes, then local correlation + normalize
    blur_k<<<dim3(2048, 4), 256, 0, stream>>>(A, B1h);
    corr2_k<<<dim3(256, 4), 256, 0, stream>>>(A, B1h, lcPad, LS);
    lc_norm_k<<<16384, 256, 0, stream>>>(lcPad, LS, 4194304);

    // fc1 (cout=128): G=4, NOC=4, WY=2 -> block 128px x 128oc; batch-phased
    for (int b = 3; b >= 0; --b)
        convmfma_k<1, 128, 2, 4, 4><<<dim3(512, 1, 1), 256, 0, stream>>>(
            A, A, 128, 128, 128, fc1W, nullptr, FC1o, 128, 0, b);
    in_stats_nhwc_k<<<dim3(128, 4), 256, 0, stream>>>(FC1o, sums0, 128, 7);
    in_finalize_k<<<2, 256, 0, stream>>>(sums0, stats0, 512);
    in_apply_nhwc_k<<<32768, 256, 0, stream>>>(FC1o, stats0, fc1_g, fc1_be, 128, 7, 8388608);

    // fc2 (cout=64): G=4, NOC=4, WY=1
    convmfma_k<1, 128, 1, 4, 4><<<dim3(256, 1, 4), 256, 0, stream>>>(
        FC1o, FC1o, 128, 128, 128, fc2W, fc2_b, featBuf, 64, 0, 0);

    // e1 (cout=64): concat(featBuf, lcPad)
    convmfma_k<1, 128, 1, 4, 4><<<dim3(256, 1, 4), 256, 0, stream>>>(
        featBuf, lcPad, 64, 64, 64, e1W, nullptr, E1o, 64, 0, 0);
    in_stats_nhwc_k<<<dim3(128, 4), 256, 0, stream>>>(E1o, sums1, 64, 6);
    in_finalize_k<<<1, 256, 0, stream>>>(sums1, stats1, 256);
    in_apply_nhwc_k<<<16384, 256, 0, stream>>>(E1o, stats1, e1_g, e1_be, 64, 6, 4194304);

    // e2 (cout=32): dil=2, G=4, NOC=2
    convmfma_k<2, 64, 1, 2, 4><<<dim3(256, 1, 4), 256, 0, stream>>>(
        E1o, E1o, 64, 64, 64, e2W, nullptr, E2o, 32, 0, 0);
    in_stats_nhwc_k<<<dim3(128, 4), 256, 0, stream>>>(E2o, sums2, 32, 5);
    in_finalize_k<<<1, 256, 0, stream>>>(sums2, stats2, 128);
    in_apply_nhwc_k<<<8192, 256, 0, stream>>>(E2o, stats2, e2_g, e2_be, 32, 5, 2097152);

    // e3 (cout=16): dil=4, G=4, NOC=1
    convmfma_k<4, 32, 1, 1, 4><<<dim3(256, 1, 4), 256, 0, stream>>>(
        E2o, E2o, 32, 32, 32, e3W, nullptr, E3o, 16, 0, 0);
    in_stats_nhwc_k<<<dim3(128, 4), 256, 0, stream>>>(E3o, sums3, 16, 4);
    in_finalize_k<<<1, 256, 0, stream>>>(sums3, stats3, 64);
    in_apply_nhwc_k<<<4096, 256, 0, stream>>>(E3o, stats3, e3_g, e3_be, 16, 4, 1048576);

    head_k<<<1024, 256, 0, stream>>>(E3o, head_w, head_b, HD);
    blur7f_k<<<dim3(256, 8), 256, 0, stream>>>(HD, out);
}

// Round 5
// 987.721 us; speedup vs baseline: 2.6293x; 1.2494x over previous
//
#include <hip/hip_runtime.h>
#include <hip/hip_bf16.h>

// ---------------------------------------------------------------------------
// DispEstimator pipeline, MFMA bf16 implicit-GEMM (R12).
// R12 = R11 (per-row LDS staging in convmfma_k, XCD-swizzled rows) with the
// fc1 batch-phasing RESTORED: FC1o[b] aliases A[b+1] in the workspace, so fc1
// must run as 4 sequential launches (b=3..0) — R11's single z=4 launch raced
// producer/consumer across batches (absmax 0.617).
// ---------------------------------------------------------------------------

typedef __attribute__((ext_vector_type(8))) short short8;
typedef __attribute__((ext_vector_type(4))) float f32x4;
typedef _Float16 f16x8 __attribute__((ext_vector_type(8)));
typedef _Float16 f16x2 __attribute__((ext_vector_type(2)));

__device__ __forceinline__ float s2f(short s) {
    unsigned int u = ((unsigned int)(unsigned short)s) << 16;
    float f; __builtin_memcpy(&f, &u, 4); return f;
}
__device__ __forceinline__ short f2s(float f) {
    __hip_bfloat16 h = __float2bfloat16(f);
    short s; __builtin_memcpy(&s, &h, 2); return s;
}
__device__ __forceinline__ float h2f(short s) {
    _Float16 h; __builtin_memcpy(&h, &s, 2); return (float)h;
}
__device__ __forceinline__ short f2h(float f) {
    _Float16 h = (_Float16)f;
    short s; __builtin_memcpy(&s, &h, 2); return s;
}

__device__ __forceinline__ float gw(int j) {
    const float G[7] = {0.0366329f, 0.1112808f, 0.2167453f, 0.2706821f,
                        0.2167453f, 0.1112808f, 0.0366329f};
    return G[j];
}

// ---------------------------------------------------------------------------
// NCHW fp32 -> NHWC bf16 transpose. grid (1024, B), block 256.
// ---------------------------------------------------------------------------
__global__ __launch_bounds__(256) void transpose_k(const float* __restrict__ in,
                                                   short* __restrict__ out)
{
    __shared__ float t[64][65];
    const int b = blockIdx.y;
    const int px0 = blockIdx.x * 64;
    #pragma unroll
    for (int k = 0; k < 16; ++k) {
        int idx = threadIdx.x + k * 256;
        int c = idx >> 6, x = idx & 63;
        t[c][x] = in[(size_t)(b * 64 + c) * 65536 + px0 + x];
    }
    __syncthreads();
    #pragma unroll
    for (int k = 0; k < 16; ++k) {
        int idx = threadIdx.x + k * 256;
        int px = idx >> 6, c = idx & 63;
        out[(size_t)(b * 65536 + px0 + px) * 64 + c] = f2s(t[c][px]);
    }
}

// ---------------------------------------------------------------------------
// Weight repack v2: [oc][cin][3][3] fp32 -> MFMA-native
// [o16][tap][cb][lane][8] bf16 (o16 = oc/16, cb = k-block of 32, lane=q*16+n16;
// element (lane,c8) <-> oc = o16*16+n16, ic = cb*32+q*8+c8). Zero-padded.
// ---------------------------------------------------------------------------
__global__ __launch_bounds__(256) void repack2_k(const float* __restrict__ w,
                                                 short* __restrict__ o,
                                                 int cout, int cin, int CINP)
{
    int idx = blockIdx.x * 256 + threadIdx.x;
    int CB = CINP >> 5;
    int tot = cout * 9 * CINP;
    if (idx >= tot) return;
    int c8   = idx & 7;
    int lane = (idx >> 3) & 63;
    int rest = idx >> 9;          // ((o16*9+tap)*CB + cb)
    int cb   = rest % CB;
    int rest2 = rest / CB;
    int tap  = rest2 % 9;
    int o16  = rest2 / 9;
    int n16 = lane & 15, q = lane >> 4;
    int oc = o16 * 16 + n16;
    int ic = cb * 32 + q * 8 + c8;
    float v = (ic < cin) ? w[(size_t)(oc * cin + ic) * 9 + tap] : 0.f;
    o[idx] = f2s(v);
}

// ---------------------------------------------------------------------------
// MFMA implicit-GEMM 3x3 conv, NHWC bf16, zero pad = DIL, LDS row staging.
// Block 256 = WX*WY waves; wave: G*16 px x 16*NOC oc. Per dy (3 rows): stage
// [PXB+2*DIL px][CINP ch] into LDS (16B units, px stride UQ+1 units), then
// 3 dx taps x CB k-blocks of MFMA reading LDS. Weights MFMA-native (repack2).
// grid:(XT*256 [/8-divisible, XCD-swizzled], cout/(16*NOC*WY), nb)
// ---------------------------------------------------------------------------
template<int DIL, int CINP, int WX, int WY, int NOC, int G>
__global__ __launch_bounds__(256) void convmfma_k(
    const short* __restrict__ srcA, const short* __restrict__ srcB,
    int splitK, int csA, int csB,
    const short* __restrict__ wgt, const float* __restrict__ bias,
    short* __restrict__ out, int OSTR, int OBASE, int b0)
{
    static_assert(WX * WY == 4, "4 waves per block");
    constexpr int PXW = G * 16;
    constexpr int PXB = PXW * WX;
    constexpr int XT  = 256 / PXB;
    constexpr int CB  = CINP / 32;
    constexpr int UQ  = CINP / 8;       // 16B units per px
    constexpr int UPX = UQ + 1;         // padded px stride (units)
    constexpr int WPX = PXB + 2 * DIL;  // staged px incl. halo

    __shared__ __align__(16) short lds[WPX * UPX * 8];

    const int tid  = threadIdx.x;
    const int lane = tid & 63;
    const int wave = tid >> 6;
    const int q = lane >> 4, n16 = lane & 15;
    const int wx = wave % WX, wy = wave / WX;

    // bijective XCD swizzle (gridDim.x = XT*256, divisible by 8)
    constexpr int NX = XT * 256;
    const int bx = blockIdx.x;
    const int xs = (bx & 7) * (NX >> 3) + (bx >> 3);
    const int xt = xs % XT;
    const int y  = xs / XT;

    const int b  = b0 + blockIdx.z;
    const int ocWaveBase = blockIdx.y * (16 * NOC * WY) + wy * (16 * NOC);
    const int o16base = ocWaveBase >> 4;
    const int x0 = xt * PXB + wx * PXW;
    const int gxbase = xt * PXB - DIL;

    f32x4 acc[G][NOC];
    #pragma unroll
    for (int g = 0; g < G; ++g)
        #pragma unroll
        for (int t = 0; t < NOC; ++t)
            acc[g][t] = {0.f, 0.f, 0.f, 0.f};

    for (int dyi = 0; dyi < 3; ++dyi) {
        const int yy = y + (dyi - 1) * DIL;
        const bool rowok = ((unsigned)yy < 256u);   // block-uniform
        __syncthreads();                            // prev readers done
        if (rowok) {
            const int rowbase = (b * 256 + yy) * 256;
            for (int i = tid; i < WPX * UQ; i += 256) {
                const int pxl = i / UQ;
                const int u   = i - pxl * UQ;
                const int gx  = gxbase + pxl;
                short8 v = {0, 0, 0, 0, 0, 0, 0, 0};
                if ((unsigned)gx < 256u) {
                    const int ic = u * 8;
                    const short* p = (ic < splitK)
                        ? srcA + (size_t)(rowbase + gx) * csA + ic
                        : srcB + (size_t)(rowbase + gx) * csB + (ic - splitK);
                    v = *reinterpret_cast<const short8*>(p);
                }
                *reinterpret_cast<short8*>(&lds[(pxl * UPX + u) * 8]) = v;
            }
        }
        __syncthreads();                            // stage visible
        if (!rowok) continue;                       // zero contribution

        #pragma unroll
        for (int dxi = 0; dxi < 3; ++dxi) {
            const int tap = dyi * 3 + dxi;
            #pragma unroll
            for (int cb = 0; cb < CB; ++cb) {
                short8 bfr[G];
                #pragma unroll
                for (int g = 0; g < G; ++g) {
                    const int pxl = wx * PXW + g * 16 + n16 + dxi * DIL;
                    bfr[g] = *reinterpret_cast<const short8*>(
                        &lds[(pxl * UPX + cb * 4 + q) * 8]);
                }
                #pragma unroll
                for (int t = 0; t < NOC; ++t) {
                    short8 a = *reinterpret_cast<const short8*>(
                        wgt + ((((size_t)(o16base + t) * 9 + tap) * CB + cb) * 64 + lane) * 8);
                    #pragma unroll
                    for (int g = 0; g < G; ++g)
                        acc[g][t] = __builtin_amdgcn_mfma_f32_16x16x32_bf16(
                            a, bfr[g], acc[g][t], 0, 0, 0);
                }
            }
        }
    }

    #pragma unroll
    for (int g = 0; g < G; ++g) {
        const size_t px_lin = (size_t)(b * 256 + y) * 256 + x0 + g * 16 + n16;
        #pragma unroll
        for (int t = 0; t < NOC; ++t) {
            const int oc = ocWaveBase + t * 16 + q * 4;
            f32x4 v = acc[g][t];
            if (bias) {
                v.x += bias[oc];     v.y += bias[oc + 1];
                v.z += bias[oc + 2]; v.w += bias[oc + 3];
            }
            ushort4 pk;
            pk.x = (unsigned short)f2s(v.x);
            pk.y = (unsigned short)f2s(v.y);
            pk.z = (unsigned short)f2s(v.z);
            pk.w = (unsigned short)f2s(v.w);
            *reinterpret_cast<ushort4*>(out + px_lin * OSTR + OBASE + oc) = pk;
        }
    }
}

// ---------------------------------------------------------------------------
// Instance-norm partial sums, NHWC. grid (128 slices, B), block 256.
// ---------------------------------------------------------------------------
__global__ __launch_bounds__(256) void in_stats_nhwc_k(const short* __restrict__ x,
                                                       float* __restrict__ sums,
                                                       int C, int lC)
{
    __shared__ float ls[256], lss[256];
    const int tid = threadIdx.x;
    const int b = blockIdx.y;
    const int c = tid & (C - 1);
    const int sub = tid >> lC;
    const int tpc = 256 >> lC;
    const int px0 = blockIdx.x * 512;
    float s = 0.f, ss = 0.f;
    for (int p = sub; p < 512; p += tpc) {
        float v = s2f(x[(size_t)(b * 65536 + px0 + p) * C + c]);
        s += v; ss += v * v;
    }
    ls[tid] = s; lss[tid] = ss;
    __syncthreads();
    if (tid < C) {
        float s0 = ls[tid], ss0 = lss[tid];
        for (int j = 1; j < tpc; ++j) { s0 += ls[tid + j * C]; ss0 += lss[tid + j * C]; }
        atomicAdd(sums + 2 * (b * C + tid), s0);
        atomicAdd(sums + 2 * (b * C + tid) + 1, ss0);
    }
}

__global__ __launch_bounds__(256) void in_finalize_k(const float* __restrict__ sums,
                                                     float* __restrict__ stats, int n)
{
    int i = blockIdx.x * 256 + threadIdx.x;
    if (i >= n) return;
    float m = sums[2 * i] * (1.f / 65536.f);
    float var = sums[2 * i + 1] * (1.f / 65536.f) - m * m;
    if (var < 0.f) var = 0.f;
    stats[2 * i] = m;
    stats[2 * i + 1] = rsqrtf(var + 1e-5f);
}

__global__ __launch_bounds__(256) void in_apply_nhwc_k(short* __restrict__ x,
                                                       const float* __restrict__ stats,
                                                       const float* __restrict__ gamma,
                                                       const float* __restrict__ beta,
                                                       int C, int lC, int n4)
{
    int i = blockIdx.x * 256 + threadIdx.x;
    if (i >= n4) return;
    int e0 = i * 4;
    int c0 = e0 & (C - 1);
    int b = e0 >> (16 + lC);
    ushort4 u = reinterpret_cast<ushort4*>(x)[i];
    unsigned short vs[4] = {u.x, u.y, u.z, u.w};
    #pragma unroll
    for (int j = 0; j < 4; ++j) {
        int bc = b * C + c0 + j;
        float t = (s2f((short)vs[j]) - stats[2 * bc]) * stats[2 * bc + 1]
                  * gamma[c0 + j] + beta[c0 + j];
        vs[j] = (unsigned short)f2s(t >= 0.f ? t : 0.2f * t);
    }
    u.x = vs[0]; u.y = vs[1]; u.z = vs[2]; u.w = vs[3];
    reinterpret_cast<ushort4*>(x)[i] = u;
}

// ---------------------------------------------------------------------------
// Separable 7x7 gaussian blur of f1 (A ch 0-63, replicate edges) -> fp16
// planes, group-major: B1[((g*4+b)<<16 | px)*8 + c].  One (16x16 tile,
// 8-ch group) per block; grid (256*8, B), block 256. LDS 24.6 KB, 2 barriers.
// ---------------------------------------------------------------------------
__global__ __launch_bounds__(256) void blur_k(const short* __restrict__ A,
                                              short* __restrict__ B1)
{
    __shared__ __align__(16) short raw[484 * 8];    // 22x22 halo, 7.7 KB
    __shared__ __align__(16) float hb[352 * 12];    // 22 rows x 16 cols, 16.9 KB

    const int tid  = threadIdx.x;
    const int tile = blockIdx.x >> 3;
    const int g    = blockIdx.x & 7;
    const int c0   = g * 8;
    const int tx = (tile & 15) << 4;
    const int ty = (tile >> 4) << 4;
    const int b  = blockIdx.y;

    #pragma unroll
    for (int it = 0; it < 2; ++it) {
        int i = tid + it * 256;
        if (i < 484) {
            int y = i / 22, x = i - y * 22;
            int gy = ty + y - 3, gx = tx + x - 3;
            gy = gy < 0 ? 0 : (gy > 255 ? 255 : gy);
            gx = gx < 0 ? 0 : (gx > 255 ? 255 : gx);
            *reinterpret_cast<short8*>(&raw[i * 8]) =
                *reinterpret_cast<const short8*>(
                    &A[(size_t)((b << 16) + (gy << 8) + gx) * 128 + c0]);
        }
    }
    __syncthreads();

    #pragma unroll
    for (int it = 0; it < 2; ++it) {
        int i = tid + it * 256;
        if (i < 352) {                       // 22 rows x 16 core cols
            int r = i >> 4, cc = i & 15;
            float s[8];
            #pragma unroll
            for (int c = 0; c < 8; ++c) s[c] = 0.f;
            #pragma unroll
            for (int j = 0; j < 7; ++j) {
                short8 v = *reinterpret_cast<const short8*>(&raw[(r * 22 + cc + j) * 8]);
                float w = gw(j);
                #pragma unroll
                for (int c = 0; c < 8; ++c) s[c] += w * s2f(v[c]);
            }
            #pragma unroll
            for (int c = 0; c < 8; ++c) hb[i * 12 + c] = s[c];
        }
    }
    __syncthreads();

    const int py = tid >> 4, px = tid & 15;
    float s[8];
    #pragma unroll
    for (int c = 0; c < 8; ++c) s[c] = 0.f;
    #pragma unroll
    for (int j = 0; j < 7; ++j) {
        const float* hp = &hb[((py + j) * 16 + px) * 12];
        float w = gw(j);
        #pragma unroll
        for (int c = 0; c < 8; ++c) s[c] += w * hp[c];
    }
    short8 ov;
    #pragma unroll
    for (int c = 0; c < 8; ++c) ov[c] = f2h(s[c]);
    *reinterpret_cast<short8*>(
        &B1[(size_t)(((g * 4 + b) << 16) + ((ty + py) << 8) + tx + px) * 8]) = ov;
}

// ---------------------------------------------------------------------------
// Local correlation from pre-blurred f1 (fp16 planes) + f2 (A ch 64-127).
// Per 8-ch group: stage 22x22 fp16 tile (16B/cell) into double-buffered LDS,
// SSD via v_pk_add_f16 + v_dot2_f32_f16 (f32 accum). 1 ds_read_b128/cell,
// 8 barriers. LDS 15.5KB. Block 256 = 16x16 px. Grid (256, B).
// ---------------------------------------------------------------------------
__global__ __launch_bounds__(256, 2) void corr2_k(const short* __restrict__ A,
                                                  const short* __restrict__ B1,
                                                  short* __restrict__ lcPad,
                                                  float* __restrict__ lcsum)
{
    __shared__ __align__(16) short blh[2][484 * 8];  // fp16 payload, 15.5 KB
    __shared__ float red[4];

    const int tid = threadIdx.x;
    const int tx = (blockIdx.x & 15) << 4;
    const int ty = (blockIdx.x >> 4) << 4;
    const int b  = blockIdx.y;
    const int py = tid >> 4, px = tid & 15;

    // Precompute staging descriptors for cells tid and tid+256 (halo +-3).
    int y0 = tid / 22, x0c = tid - y0 * 22;
    int gy0 = ty + y0 - 3, gx0 = tx + x0c - 3;
    const bool ok0 = (gy0 >= 0 && gy0 < 256 && gx0 >= 0 && gx0 < 256);
    gy0 = gy0 < 0 ? 0 : (gy0 > 255 ? 255 : gy0);
    gx0 = gx0 < 0 ? 0 : (gx0 > 255 ? 255 : gx0);
    const int off0 = (gy0 << 8) + gx0;

    const int c1 = tid + 256;
    int y1 = c1 / 22, x1c = c1 - y1 * 22;
    int gy1 = ty + y1 - 3, gx1 = tx + x1c - 3;
    const bool ok1 = (gy1 >= 0 && gy1 < 256 && gx1 >= 0 && gx1 < 256);
    gy1 = gy1 < 0 ? 0 : (gy1 > 255 ? 255 : gy1);
    gx1 = gx1 < 0 ? 0 : (gx1 > 255 ? 255 : gx1);
    const int off1 = (gy1 << 8) + gx1;
    const bool has1 = (c1 < 484);

    const short* f2p = &A[(size_t)((b << 16) + ((ty + py) << 8) + tx + px) * 128 + 64];

    float acc[49];
    #pragma unroll
    for (int k = 0; k < 49; ++k) acc[k] = 0.f;

    for (int g = 0; g < 8; ++g) {
        const size_t plane = (size_t)(g * 4 + b) << 16;
        short* buf = blh[g & 1];

        // stage fp16 tile (pure copy, masked to zero outside image)
        {
            short8 v = *reinterpret_cast<const short8*>(&B1[(plane + off0) * 8]);
            if (!ok0) v = v ^ v;
            *reinterpret_cast<short8*>(&buf[tid * 8]) = v;
            if (has1) {
                short8 w = *reinterpret_cast<const short8*>(&B1[(plane + off1) * 8]);
                if (!ok1) w = w ^ w;
                *reinterpret_cast<short8*>(&buf[c1 * 8]) = w;
            }
        }

        // f2 (bf16) -> fp16 registers
        short8 f2raw = *reinterpret_cast<const short8*>(f2p + g * 8);
        f16x8 f2v;
        #pragma unroll
        for (int c = 0; c < 8; ++c) f2v[c] = (_Float16)s2f(f2raw[c]);

        __syncthreads();

        const short* blp = &buf[(py * 22 + px) * 8];
        #pragma unroll
        for (int i = 0; i < 7; ++i)
            #pragma unroll
            for (int j = 0; j < 7; ++j) {
                f16x8 bv = *reinterpret_cast<const f16x8*>(blp + (i * 22 + j) * 8);
                f16x8 d = f2v - bv;
                float a = acc[i * 7 + j];
#if __has_builtin(__builtin_amdgcn_fdot2)
                a = __builtin_amdgcn_fdot2(__builtin_shufflevector(d, d, 0, 1),
                                           __builtin_shufflevector(d, d, 0, 1), a, false);
                a = __builtin_amdgcn_fdot2(__builtin_shufflevector(d, d, 2, 3),
                                           __builtin_shufflevector(d, d, 2, 3), a, false);
                a = __builtin_amdgcn_fdot2(__builtin_shufflevector(d, d, 4, 5),
                                           __builtin_shufflevector(d, d, 4, 5), a, false);
                a = __builtin_amdgcn_fdot2(__builtin_shufflevector(d, d, 6, 7),
                                           __builtin_shufflevector(d, d, 6, 7), a, false);
#else
                #pragma unroll
                for (int c = 0; c < 8; ++c) {
                    float df = (float)d[c];
                    a += df * df;
                }
#endif
                acc[i * 7 + j] = a;
            }
        // no trailing barrier: next g writes the other buffer; the barrier
        // of iteration g+1 orders our reads of buf[g&1] before g+2's writes.
    }

    const size_t base = (size_t)((b << 16) + ((ty + py) << 8) + tx + px) * 64;
    float tot = 0.f;
    #pragma unroll
    for (int k = 0; k < 49; ++k) {
        float m = acc[k] * (1.f / 64.f);
        lcPad[base + k] = f2s(m);
        tot += m;
    }
    #pragma unroll
    for (int k = 49; k < 64; ++k) lcPad[base + k] = 0;

    for (int o = 32; o; o >>= 1) tot += __shfl_down(tot, o);
    if ((tid & 63) == 0) red[tid >> 6] = tot;
    __syncthreads();
    if (tid == 0) atomicAdd(lcsum + b, red[0] + red[1] + red[2] + red[3]);
}

__global__ __launch_bounds__(256) void lc_norm_k(short* __restrict__ lc,
                                                 const float* __restrict__ ls, int n4)
{
    int i = blockIdx.x * 256 + threadIdx.x;
    if (i >= n4) return;
    int b = (i * 4) >> 22;
    float sc = 1.f / (ls[b] * (1.f / 3211264.f) + 1e-6f);
    ushort4 u = reinterpret_cast<ushort4*>(lc)[i];
    u.x = (unsigned short)f2s(s2f((short)u.x) * sc);
    u.y = (unsigned short)f2s(s2f((short)u.y) * sc);
    u.z = (unsigned short)f2s(s2f((short)u.z) * sc);
    u.w = (unsigned short)f2s(s2f((short)u.w) * sc);
    reinterpret_cast<ushort4*>(lc)[i] = u;
}

// ---------------------------------------------------------------------------
// Head conv: NHWC bf16 [b,px,16] -> NCHW fp32 planes [b*2+oc][px].
// ---------------------------------------------------------------------------
__global__ __launch_bounds__(256) void head_k(const short* __restrict__ e3,
                                              const float* __restrict__ w,
                                              const float* __restrict__ bias,
                                              float* __restrict__ hd)
{
    int pix = blockIdx.x * 256 + threadIdx.x;
    int b = pix >> 16, rem = pix & 65535;
    int y = rem >> 8, x = rem & 255;
    float a0 = bias[0], a1 = bias[1];
    #pragma unroll
    for (int tap = 0; tap < 9; ++tap) {
        int yy = y + tap / 3 - 1, xx = x + tap % 3 - 1;
        if ((unsigned)yy >= 256u || (unsigned)xx >= 256u) continue;
        const short* p = e3 + (size_t)((b << 16) + (yy << 8) + xx) * 16;
        #pragma unroll
        for (int ic = 0; ic < 16; ++ic) {
            float v = s2f(p[ic]);
            a0 += v * w[ic * 9 + tap];
            a1 += v * w[(16 + ic) * 9 + tap];
        }
    }
    hd[(size_t)(b * 2) * 65536 + rem]     = a0;
    hd[(size_t)(b * 2 + 1) * 65536 + rem] = a1;
}

// ---------------------------------------------------------------------------
// Final separable 7-tap gaussian blur (replicate edges), fp32 planes.
// ---------------------------------------------------------------------------
__global__ __launch_bounds__(256) void blur7f_k(const float* __restrict__ in,
                                                float* __restrict__ out)
{
    __shared__ float raw[22 * 22];
    __shared__ float hb[22 * 16];
    const int tid = threadIdx.x;
    const int tx = (blockIdx.x & 15) << 4;
    const int ty = (blockIdx.x >> 4) << 4;
    const size_t ch = ((size_t)blockIdx.y) << 16;
    const int py = tid >> 4, px = tid & 15;

    for (int i = tid; i < 484; i += 256) {
        int y = i / 22, x = i - y * 22;
        int gy = ty + y - 3, gx = tx + x - 3;
        gy = gy < 0 ? 0 : (gy > 255 ? 255 : gy);
        gx = gx < 0 ? 0 : (gx > 255 ? 255 : gx);
        raw[i] = in[ch + (gy << 8) + gx];
    }
    __syncthreads();
    for (int i = tid; i < 352; i += 256) {
        int r = i >> 4, cc = i & 15;
        float s = 0.f;
        #pragma unroll
        for (int j = 0; j < 7; ++j) s += gw(j) * raw[r * 22 + cc + j];
        hb[i] = s;
    }
    __syncthreads();
    float s = 0.f;
    #pragma unroll
    for (int j = 0; j < 7; ++j) s += gw(j) * hb[(py + j) * 16 + px];
    out[ch + ((ty + py) << 8) + tx + px] = s;
}

// ---------------------------------------------------------------------------
extern "C" void kernel_launch(void* const* d_in, const int* in_sizes, int n_in,
                              void* d_out, int out_size, void* d_ws, size_t ws_size,
                              hipStream_t stream)
{
    const float* feat1  = (const float*)d_in[0];
    const float* feat2  = (const float*)d_in[1];
    const float* pre_w  = (const float*)d_in[2];
    const float* pre_b  = (const float*)d_in[3];
    const float* fc1_w  = (const float*)d_in[4];
    const float* fc1_g  = (const float*)d_in[5];
    const float* fc1_be = (const float*)d_in[6];
    const float* fc2_w  = (const float*)d_in[7];
    const float* fc2_b  = (const float*)d_in[8];
    const float* e1_w   = (const float*)d_in[9];
    const float* e1_g   = (const float*)d_in[10];
    const float* e1_be  = (const float*)d_in[11];
    const float* e2_w   = (const float*)d_in[12];
    const float* e2_g   = (const float*)d_in[13];
    const float* e2_be  = (const float*)d_in[14];
    const float* e3_w   = (const float*)d_in[15];
    const float* e3_g   = (const float*)d_in[16];
    const float* e3_be  = (const float*)d_in[17];
    const float* head_w = (const float*)d_in[18];
    const float* head_b = (const float*)d_in[19];
    float* out = (float*)d_out;

    const size_t NEED = 152000000;
    if (ws_size < NEED) return;

    char* ws = (char*)d_ws;
    short* T1      = (short*)(ws);
    short* T2      = (short*)(ws + 33554432);
    short* lcPad   = (short*)(ws);
    short* B1h     = (short*)(ws + 33554432);   // blurred f1, fp16 group-major
    short* featBuf = (short*)(ws + 33554432);
    short* A       = (short*)(ws + 67108864);
    short* FC1o    = (short*)(ws + 83886080);
    short* E1o     = (short*)(ws + 67108864);
    short* E2o     = (short*)(ws + 100663296);
    short* E3o     = (short*)(ws + 117440512);
    float* HD      = (float*)(ws + 125829120);
    short* preW    = (short*)(ws + 150994944);
    short* fc1W    = (short*)(ws + 151068672);
    short* fc2W    = (short*)(ws + 151363584);
    short* e1W     = (short*)(ws + 151511040);
    short* e2W     = (short*)(ws + 151658496);
    short* e3W     = (short*)(ws + 151695360);
    float* sums0   = (float*)(ws + 151704576);
    float* sums1   = (float*)(ws + 151708672);
    float* sums2   = (float*)(ws + 151712768);
    float* sums3   = (float*)(ws + 151716864);
    float* stats0  = (float*)(ws + 151720960);
    float* stats1  = (float*)(ws + 151725056);
    float* stats2  = (float*)(ws + 151729152);
    float* stats3  = (float*)(ws + 151733248);
    float* LS      = (float*)(ws + 151737344);

    hipMemsetAsync(ws + 151704576, 0, 32784, stream);

    transpose_k<<<dim3(1024, 4), 256, 0, stream>>>(feat1, T1);
    transpose_k<<<dim3(1024, 4), 256, 0, stream>>>(feat2, T2);

    repack2_k<<<144, 256, 0, stream>>>(pre_w, preW, 64, 64, 64);
    repack2_k<<<576, 256, 0, stream>>>(fc1_w, fc1W, 128, 128, 128);
    repack2_k<<<288, 256, 0, stream>>>(fc2_w, fc2W, 64, 128, 128);
    repack2_k<<<288, 256, 0, stream>>>(e1_w, e1W, 64, 113, 128);
    repack2_k<<<72, 256, 0, stream>>>(e2_w, e2W, 32, 64, 64);
    repack2_k<<<18, 256, 0, stream>>>(e3_w, e3W, 16, 32, 32);

    // pre conv (cout=64): WX=2,WY=2,NOC=2 -> 128px x 64oc blocks, LDS 18.7KB
    convmfma_k<1, 64, 2, 2, 2, 4><<<dim3(512, 1, 4), 256, 0, stream>>>(
        T1, T1, 64, 64, 64, preW, pre_b, A, 128, 0, 0);
    convmfma_k<1, 64, 2, 2, 2, 4><<<dim3(512, 1, 4), 256, 0, stream>>>(
        T2, T2, 64, 64, 64, preW, pre_b, A, 128, 64, 0);

    // blur f1 -> fp16 planes, then local correlation + normalize
    blur_k<<<dim3(2048, 4), 256, 0, stream>>>(A, B1h);
    corr2_k<<<dim3(256, 4), 256, 0, stream>>>(A, B1h, lcPad, LS);
    lc_norm_k<<<16384, 256, 0, stream>>>(lcPad, LS, 4194304);

    // fc1 (cout=128): WX=2,WY=2,NOC=4 -> 128px x 128oc blocks, LDS 35.4KB
    // MUST stay batch-phased (b=3..0): FC1o[b] aliases A[b+1] in workspace.
    for (int b = 3; b >= 0; --b)
        convmfma_k<1, 128, 2, 2, 4, 4><<<dim3(512, 1, 1), 256, 0, stream>>>(
            A, A, 128, 128, 128, fc1W, nullptr, FC1o, 128, 0, b);
    in_stats_nhwc_k<<<dim3(128, 4), 256, 0, stream>>>(FC1o, sums0, 128, 7);
    in_finalize_k<<<2, 256, 0, stream>>>(sums0, stats0, 512);
    in_apply_nhwc_k<<<32768, 256, 0, stream>>>(FC1o, stats0, fc1_g, fc1_be, 128, 7, 8388608);

    // fc2 (cout=64): WX=2,WY=2,NOC=2, LDS 35.4KB
    convmfma_k<1, 128, 2, 2, 2, 4><<<dim3(512, 1, 4), 256, 0, stream>>>(
        FC1o, FC1o, 128, 128, 128, fc2W, fc2_b, featBuf, 64, 0, 0);

    // e1 (cout=64): concat(featBuf, lcPad), WX=2,WY=2,NOC=2
    convmfma_k<1, 128, 2, 2, 2, 4><<<dim3(512, 1, 4), 256, 0, stream>>>(
        featBuf, lcPad, 64, 64, 64, e1W, nullptr, E1o, 64, 0, 0);
    in_stats_nhwc_k<<<dim3(128, 4), 256, 0, stream>>>(E1o, sums1, 64, 6);
    in_finalize_k<<<1, 256, 0, stream>>>(sums1, stats1, 256);
    in_apply_nhwc_k<<<16384, 256, 0, stream>>>(E1o, stats1, e1_g, e1_be, 64, 6, 4194304);

    // e2 (cout=32): dil=2, WX=2,WY=2,NOC=1, LDS 19KB
    convmfma_k<2, 64, 2, 2, 1, 4><<<dim3(512, 1, 4), 256, 0, stream>>>(
        E1o, E1o, 64, 64, 64, e2W, nullptr, E2o, 32, 0, 0);
    in_stats_nhwc_k<<<dim3(128, 4), 256, 0, stream>>>(E2o, sums2, 32, 5);
    in_finalize_k<<<1, 256, 0, stream>>>(sums2, stats2, 128);
    in_apply_nhwc_k<<<8192, 256, 0, stream>>>(E2o, stats2, e2_g, e2_be, 32, 5, 2097152);

    // e3 (cout=16): dil=4, WX=4,WY=1,NOC=1 -> 256px x 16oc blocks, LDS 21.1KB
    convmfma_k<4, 32, 4, 1, 1, 4><<<dim3(256, 1, 4), 256, 0, stream>>>(
        E2o, E2o, 32, 32, 32, e3W, nullptr, E3o, 16, 0, 0);
    in_stats_nhwc_k<<<dim3(128, 4), 256, 0, stream>>>(E3o, sums3, 16, 4);
    in_finalize_k<<<1, 256, 0, stream>>>(sums3, stats3, 64);
    in_apply_nhwc_k<<<4096, 256, 0, stream>>>(E3o, stats3, e3_g, e3_be, 16, 4, 1048576);

    head_k<<<1024, 256, 0, stream>>>(E3o, head_w, head_b, HD);
    blur7f_k<<<dim3(256, 8), 256, 0, stream>>>(HD, out);
}

// Round 6
// 965.557 us; speedup vs baseline: 2.6897x; 1.0230x over previous
//
#include <hip/hip_runtime.h>
#include <hip/hip_bf16.h>

// ---------------------------------------------------------------------------
// DispEstimator pipeline, MFMA bf16 implicit-GEMM (R13).
// R13: fuse elementwise passes into conv LDS staging:
//  - in_finalize emits (ka=rsqrt*gamma, kb=beta-m*ka); conv MODE1 applies
//    x*ka+kb then lrelu (fmax(t,.2t)) while staging (fc2/e2/e3 inputs);
//    MODE2 scales the lcPad half by the lc normalizer during e1 staging;
//    head_k applies e3's IN+lrelu inline.
//  - removes in_apply x4 + lc_norm (~307MB HBM traffic, 5 launches).
//  - corr2_k LDS row stride 22->24 cells (bank alignment experiment).
// ---------------------------------------------------------------------------

typedef __attribute__((ext_vector_type(8))) short short8;
typedef __attribute__((ext_vector_type(4))) float f32x4;
typedef _Float16 f16x8 __attribute__((ext_vector_type(8)));

__device__ __forceinline__ float s2f(short s) {
    unsigned int u = ((unsigned int)(unsigned short)s) << 16;
    float f; __builtin_memcpy(&f, &u, 4); return f;
}
__device__ __forceinline__ short f2s(float f) {
    __hip_bfloat16 h = __float2bfloat16(f);
    short s; __builtin_memcpy(&s, &h, 2); return s;
}
__device__ __forceinline__ short f2h(float f) {
    _Float16 h = (_Float16)f;
    short s; __builtin_memcpy(&s, &h, 2); return s;
}

__device__ __forceinline__ float gw(int j) {
    const float G[7] = {0.0366329f, 0.1112808f, 0.2167453f, 0.2706821f,
                        0.2167453f, 0.1112808f, 0.0366329f};
    return G[j];
}

// ---------------------------------------------------------------------------
// NCHW fp32 -> NHWC bf16 transpose. grid (1024, B), block 256.
// ---------------------------------------------------------------------------
__global__ __launch_bounds__(256) void transpose_k(const float* __restrict__ in,
                                                   short* __restrict__ out)
{
    __shared__ float t[64][65];
    const int b = blockIdx.y;
    const int px0 = blockIdx.x * 64;
    #pragma unroll
    for (int k = 0; k < 16; ++k) {
        int idx = threadIdx.x + k * 256;
        int c = idx >> 6, x = idx & 63;
        t[c][x] = in[(size_t)(b * 64 + c) * 65536 + px0 + x];
    }
    __syncthreads();
    #pragma unroll
    for (int k = 0; k < 16; ++k) {
        int idx = threadIdx.x + k * 256;
        int px = idx >> 6, c = idx & 63;
        out[(size_t)(b * 65536 + px0 + px) * 64 + c] = f2s(t[c][px]);
    }
}

// ---------------------------------------------------------------------------
// Weight repack v2: [oc][cin][3][3] fp32 -> MFMA-native
// [o16][tap][cb][lane][8] bf16. Zero-padded.
// ---------------------------------------------------------------------------
__global__ __launch_bounds__(256) void repack2_k(const float* __restrict__ w,
                                                 short* __restrict__ o,
                                                 int cout, int cin, int CINP)
{
    int idx = blockIdx.x * 256 + threadIdx.x;
    int CB = CINP >> 5;
    int tot = cout * 9 * CINP;
    if (idx >= tot) return;
    int c8   = idx & 7;
    int lane = (idx >> 3) & 63;
    int rest = idx >> 9;          // ((o16*9+tap)*CB + cb)
    int cb   = rest % CB;
    int rest2 = rest / CB;
    int tap  = rest2 % 9;
    int o16  = rest2 / 9;
    int n16 = lane & 15, q = lane >> 4;
    int oc = o16 * 16 + n16;
    int ic = cb * 32 + q * 8 + c8;
    float v = (ic < cin) ? w[(size_t)(oc * cin + ic) * 9 + tap] : 0.f;
    o[idx] = f2s(v);
}

// ---------------------------------------------------------------------------
// MFMA implicit-GEMM 3x3 conv, NHWC bf16, zero pad = DIL, LDS row staging.
// MODE 0: plain staging. MODE 1: apply x*ka+kb then lrelu while staging
// (xf = (ka,kb) table, indexed 2*(b*CINP+ic)). MODE 2: scale channels
// ic>=splitK by sc=1/(xf[b]/3211264+1e-6) (lc normalization, e1).
// Out-of-range pixels stay exactly zero (pad-after-norm semantics).
// grid:(XT*256 [/8-divisible, XCD-swizzled], cout/(16*NOC*WY), nb)
// ---------------------------------------------------------------------------
template<int DIL, int CINP, int WX, int WY, int NOC, int G, int MODE>
__global__ __launch_bounds__(256) void convmfma_k(
    const short* __restrict__ srcA, const short* __restrict__ srcB,
    int splitK, int csA, int csB,
    const short* __restrict__ wgt, const float* __restrict__ bias,
    short* __restrict__ out, int OSTR, int OBASE, int b0,
    const float* __restrict__ xf)
{
    static_assert(WX * WY == 4, "4 waves per block");
    constexpr int PXW = G * 16;
    constexpr int PXB = PXW * WX;
    constexpr int XT  = 256 / PXB;
    constexpr int CB  = CINP / 32;
    constexpr int UQ  = CINP / 8;       // 16B units per px
    constexpr int UPX = UQ + 1;         // padded px stride (units)
    constexpr int WPX = PXB + 2 * DIL;  // staged px incl. halo

    __shared__ __align__(16) short lds[WPX * UPX * 8];

    const int tid  = threadIdx.x;
    const int lane = tid & 63;
    const int wave = tid >> 6;
    const int q = lane >> 4, n16 = lane & 15;
    const int wx = wave % WX, wy = wave / WX;

    // bijective XCD swizzle (gridDim.x = XT*256, divisible by 8)
    constexpr int NX = XT * 256;
    const int bx = blockIdx.x;
    const int xs = (bx & 7) * (NX >> 3) + (bx >> 3);
    const int xt = xs % XT;
    const int y  = xs / XT;

    const int b  = b0 + blockIdx.z;
    const int ocWaveBase = blockIdx.y * (16 * NOC * WY) + wy * (16 * NOC);
    const int o16base = ocWaveBase >> 4;
    const int x0 = xt * PXB + wx * PXW;
    const int gxbase = xt * PXB - DIL;

    const int bC = b * CINP;
    const float sc = (MODE == 2) ? 1.f / (xf[b] * (1.f / 3211264.f) + 1e-6f) : 0.f;

    f32x4 acc[G][NOC];
    #pragma unroll
    for (int g = 0; g < G; ++g)
        #pragma unroll
        for (int t = 0; t < NOC; ++t)
            acc[g][t] = {0.f, 0.f, 0.f, 0.f};

    for (int dyi = 0; dyi < 3; ++dyi) {
        const int yy = y + (dyi - 1) * DIL;
        const bool rowok = ((unsigned)yy < 256u);   // block-uniform
        __syncthreads();                            // prev readers done
        if (rowok) {
            const int rowbase = (b * 256 + yy) * 256;
            for (int i = tid; i < WPX * UQ; i += 256) {
                const int pxl = i / UQ;
                const int u   = i - pxl * UQ;
                const int gx  = gxbase + pxl;
                short8 v = {0, 0, 0, 0, 0, 0, 0, 0};
                if ((unsigned)gx < 256u) {
                    const int ic = u * 8;
                    const short* p = (ic < splitK)
                        ? srcA + (size_t)(rowbase + gx) * csA + ic
                        : srcB + (size_t)(rowbase + gx) * csB + (ic - splitK);
                    v = *reinterpret_cast<const short8*>(p);
                    if (MODE == 1) {
                        #pragma unroll
                        for (int c = 0; c < 8; ++c) {
                            const float ka = xf[2 * (bC + ic + c)];
                            const float kb = xf[2 * (bC + ic + c) + 1];
                            float t = s2f(v[c]) * ka + kb;
                            t = fmaxf(t, 0.2f * t);
                            v[c] = f2s(t);
                        }
                    } else if (MODE == 2) {
                        if (ic >= splitK) {
                            #pragma unroll
                            for (int c = 0; c < 8; ++c)
                                v[c] = f2s(s2f(v[c]) * sc);
                        }
                    }
                }
                *reinterpret_cast<short8*>(&lds[(pxl * UPX + u) * 8]) = v;
            }
        }
        __syncthreads();                            // stage visible
        if (!rowok) continue;                       // zero contribution

        #pragma unroll
        for (int dxi = 0; dxi < 3; ++dxi) {
            const int tap = dyi * 3 + dxi;
            #pragma unroll
            for (int cb = 0; cb < CB; ++cb) {
                short8 bfr[G];
                #pragma unroll
                for (int g = 0; g < G; ++g) {
                    const int pxl = wx * PXW + g * 16 + n16 + dxi * DIL;
                    bfr[g] = *reinterpret_cast<const short8*>(
                        &lds[(pxl * UPX + cb * 4 + q) * 8]);
                }
                #pragma unroll
                for (int t = 0; t < NOC; ++t) {
                    short8 a = *reinterpret_cast<const short8*>(
                        wgt + ((((size_t)(o16base + t) * 9 + tap) * CB + cb) * 64 + lane) * 8);
                    #pragma unroll
                    for (int g = 0; g < G; ++g)
                        acc[g][t] = __builtin_amdgcn_mfma_f32_16x16x32_bf16(
                            a, bfr[g], acc[g][t], 0, 0, 0);
                }
            }
        }
    }

    #pragma unroll
    for (int g = 0; g < G; ++g) {
        const size_t px_lin = (size_t)(b * 256 + y) * 256 + x0 + g * 16 + n16;
        #pragma unroll
        for (int t = 0; t < NOC; ++t) {
            const int oc = ocWaveBase + t * 16 + q * 4;
            f32x4 v = acc[g][t];
            if (bias) {
                v.x += bias[oc];     v.y += bias[oc + 1];
                v.z += bias[oc + 2]; v.w += bias[oc + 3];
            }
            ushort4 pk;
            pk.x = (unsigned short)f2s(v.x);
            pk.y = (unsigned short)f2s(v.y);
            pk.z = (unsigned short)f2s(v.z);
            pk.w = (unsigned short)f2s(v.w);
            *reinterpret_cast<ushort4*>(out + px_lin * OSTR + OBASE + oc) = pk;
        }
    }
}

// ---------------------------------------------------------------------------
// Instance-norm partial sums, NHWC. grid (128 slices, B), block 256.
// ---------------------------------------------------------------------------
__global__ __launch_bounds__(256) void in_stats_nhwc_k(const short* __restrict__ x,
                                                       float* __restrict__ sums,
                                                       int C, int lC)
{
    __shared__ float ls[256], lss[256];
    const int tid = threadIdx.x;
    const int b = blockIdx.y;
    const int c = tid & (C - 1);
    const int sub = tid >> lC;
    const int tpc = 256 >> lC;
    const int px0 = blockIdx.x * 512;
    float s = 0.f, ss = 0.f;
    for (int p = sub; p < 512; p += tpc) {
        float v = s2f(x[(size_t)(b * 65536 + px0 + p) * C + c]);
        s += v; ss += v * v;
    }
    ls[tid] = s; lss[tid] = ss;
    __syncthreads();
    if (tid < C) {
        float s0 = ls[tid], ss0 = lss[tid];
        for (int j = 1; j < tpc; ++j) { s0 += ls[tid + j * C]; ss0 += lss[tid + j * C]; }
        atomicAdd(sums + 2 * (b * C + tid), s0);
        atomicAdd(sums + 2 * (b * C + tid) + 1, ss0);
    }
}

// Emits (ka, kb): apply = x*ka + kb (ka = rsqrt*gamma, kb = beta - m*ka).
__global__ __launch_bounds__(256) void in_finalize_k(const float* __restrict__ sums,
                                                     float* __restrict__ stats,
                                                     const float* __restrict__ gamma,
                                                     const float* __restrict__ beta,
                                                     int lC, int n)
{
    int i = blockIdx.x * 256 + threadIdx.x;
    if (i >= n) return;
    int c = i & ((1 << lC) - 1);
    float m = sums[2 * i] * (1.f / 65536.f);
    float var = sums[2 * i + 1] * (1.f / 65536.f) - m * m;
    if (var < 0.f) var = 0.f;
    float ka = rsqrtf(var + 1e-5f) * gamma[c];
    stats[2 * i] = ka;
    stats[2 * i + 1] = beta[c] - m * ka;
}

// ---------------------------------------------------------------------------
// Separable 7x7 gaussian blur of f1 (A ch 0-63, replicate edges) -> fp16
// planes, group-major: B1[((g*4+b)<<16 | px)*8 + c]. grid (256*8, B).
// ---------------------------------------------------------------------------
__global__ __launch_bounds__(256) void blur_k(const short* __restrict__ A,
                                              short* __restrict__ B1)
{
    __shared__ __align__(16) short raw[484 * 8];    // 22x22 halo, 7.7 KB
    __shared__ __align__(16) float hb[352 * 12];    // 22 rows x 16 cols, 16.9 KB

    const int tid  = threadIdx.x;
    const int tile = blockIdx.x >> 3;
    const int g    = blockIdx.x & 7;
    const int c0   = g * 8;
    const int tx = (tile & 15) << 4;
    const int ty = (tile >> 4) << 4;
    const int b  = blockIdx.y;

    #pragma unroll
    for (int it = 0; it < 2; ++it) {
        int i = tid + it * 256;
        if (i < 484) {
            int y = i / 22, x = i - y * 22;
            int gy = ty + y - 3, gx = tx + x - 3;
            gy = gy < 0 ? 0 : (gy > 255 ? 255 : gy);
            gx = gx < 0 ? 0 : (gx > 255 ? 255 : gx);
            *reinterpret_cast<short8*>(&raw[i * 8]) =
                *reinterpret_cast<const short8*>(
                    &A[(size_t)((b << 16) + (gy << 8) + gx) * 128 + c0]);
        }
    }
    __syncthreads();

    #pragma unroll
    for (int it = 0; it < 2; ++it) {
        int i = tid + it * 256;
        if (i < 352) {                       // 22 rows x 16 core cols
            int r = i >> 4, cc = i & 15;
            float s[8];
            #pragma unroll
            for (int c = 0; c < 8; ++c) s[c] = 0.f;
            #pragma unroll
            for (int j = 0; j < 7; ++j) {
                short8 v = *reinterpret_cast<const short8*>(&raw[(r * 22 + cc + j) * 8]);
                float w = gw(j);
                #pragma unroll
                for (int c = 0; c < 8; ++c) s[c] += w * s2f(v[c]);
            }
            #pragma unroll
            for (int c = 0; c < 8; ++c) hb[i * 12 + c] = s[c];
        }
    }
    __syncthreads();

    const int py = tid >> 4, px = tid & 15;
    float s[8];
    #pragma unroll
    for (int c = 0; c < 8; ++c) s[c] = 0.f;
    #pragma unroll
    for (int j = 0; j < 7; ++j) {
        const float* hp = &hb[((py + j) * 16 + px) * 12];
        float w = gw(j);
        #pragma unroll
        for (int c = 0; c < 8; ++c) s[c] += w * hp[c];
    }
    short8 ov;
    #pragma unroll
    for (int c = 0; c < 8; ++c) ov[c] = f2h(s[c]);
    *reinterpret_cast<short8*>(
        &B1[(size_t)(((g * 4 + b) << 16) + ((ty + py) << 8) + tx + px) * 8]) = ov;
}

// ---------------------------------------------------------------------------
// Local correlation from pre-blurred f1 (fp16 planes) + f2 (A ch 64-127).
// fp16 LDS tiles (row stride 24 cells for bank alignment), double-buffered,
// v_dot2_f32_f16 SSD. Writes UN-normalized lc (e1 staging applies the scale).
// ---------------------------------------------------------------------------
__global__ __launch_bounds__(256, 2) void corr2_k(const short* __restrict__ A,
                                                  const short* __restrict__ B1,
                                                  short* __restrict__ lcPad,
                                                  float* __restrict__ lcsum)
{
    __shared__ __align__(16) short blh[2][22 * 24 * 8];  // 16.5 KB
    __shared__ float red[4];

    const int tid = threadIdx.x;
    const int tx = (blockIdx.x & 15) << 4;
    const int ty = (blockIdx.x >> 4) << 4;
    const int b  = blockIdx.y;
    const int py = tid >> 4, px = tid & 15;

    // Staging descriptors for cells tid and tid+256 (halo +-3).
    int y0 = tid / 22, x0c = tid - y0 * 22;
    int gy0 = ty + y0 - 3, gx0 = tx + x0c - 3;
    const bool ok0 = (gy0 >= 0 && gy0 < 256 && gx0 >= 0 && gx0 < 256);
    gy0 = gy0 < 0 ? 0 : (gy0 > 255 ? 255 : gy0);
    gx0 = gx0 < 0 ? 0 : (gx0 > 255 ? 255 : gx0);
    const int off0 = (gy0 << 8) + gx0;
    const int lc0 = y0 * 24 + x0c;

    const int c1 = tid + 256;
    int y1 = c1 / 22, x1c = c1 - y1 * 22;
    int gy1 = ty + y1 - 3, gx1 = tx + x1c - 3;
    const bool ok1 = (gy1 >= 0 && gy1 < 256 && gx1 >= 0 && gx1 < 256);
    gy1 = gy1 < 0 ? 0 : (gy1 > 255 ? 255 : gy1);
    gx1 = gx1 < 0 ? 0 : (gx1 > 255 ? 255 : gx1);
    const int off1 = (gy1 << 8) + gx1;
    const int lc1 = y1 * 24 + x1c;
    const bool has1 = (c1 < 484);

    const short* f2p = &A[(size_t)((b << 16) + ((ty + py) << 8) + tx + px) * 128 + 64];

    float acc[49];
    #pragma unroll
    for (int k = 0; k < 49; ++k) acc[k] = 0.f;

    for (int g = 0; g < 8; ++g) {
        const size_t plane = (size_t)(g * 4 + b) << 16;
        short* buf = blh[g & 1];

        {
            short8 v = *reinterpret_cast<const short8*>(&B1[(plane + off0) * 8]);
            if (!ok0) v = v ^ v;
            *reinterpret_cast<short8*>(&buf[lc0 * 8]) = v;
            if (has1) {
                short8 w = *reinterpret_cast<const short8*>(&B1[(plane + off1) * 8]);
                if (!ok1) w = w ^ w;
                *reinterpret_cast<short8*>(&buf[lc1 * 8]) = w;
            }
        }

        short8 f2raw = *reinterpret_cast<const short8*>(f2p + g * 8);
        f16x8 f2v;
        #pragma unroll
        for (int c = 0; c < 8; ++c) f2v[c] = (_Float16)s2f(f2raw[c]);

        __syncthreads();

        const short* blp = &buf[(py * 24 + px) * 8];
        #pragma unroll
        for (int i = 0; i < 7; ++i)
            #pragma unroll
            for (int j = 0; j < 7; ++j) {
                f16x8 bv = *reinterpret_cast<const f16x8*>(blp + (i * 24 + j) * 8);
                f16x8 d = f2v - bv;
                float a = acc[i * 7 + j];
#if __has_builtin(__builtin_amdgcn_fdot2)
                a = __builtin_amdgcn_fdot2(__builtin_shufflevector(d, d, 0, 1),
                                           __builtin_shufflevector(d, d, 0, 1), a, false);
                a = __builtin_amdgcn_fdot2(__builtin_shufflevector(d, d, 2, 3),
                                           __builtin_shufflevector(d, d, 2, 3), a, false);
                a = __builtin_amdgcn_fdot2(__builtin_shufflevector(d, d, 4, 5),
                                           __builtin_shufflevector(d, d, 4, 5), a, false);
                a = __builtin_amdgcn_fdot2(__builtin_shufflevector(d, d, 6, 7),
                                           __builtin_shufflevector(d, d, 6, 7), a, false);
#else
                #pragma unroll
                for (int c = 0; c < 8; ++c) {
                    float df = (float)d[c];
                    a += df * df;
                }
#endif
                acc[i * 7 + j] = a;
            }
        __syncthreads();
    }

    const size_t base = (size_t)((b << 16) + ((ty + py) << 8) + tx + px) * 64;
    float tot = 0.f;
    #pragma unroll
    for (int k = 0; k < 49; ++k) {
        float m = acc[k] * (1.f / 64.f);
        lcPad[base + k] = f2s(m);
        tot += m;
    }
    #pragma unroll
    for (int k = 49; k < 64; ++k) lcPad[base + k] = 0;

    for (int o = 32; o; o >>= 1) tot += __shfl_down(tot, o);
    if ((tid & 63) == 0) red[tid >> 6] = tot;
    __syncthreads();
    if (tid == 0) atomicAdd(lcsum + b, red[0] + red[1] + red[2] + red[3]);
}

// ---------------------------------------------------------------------------
// Head conv: applies e3's IN+lrelu (ka,kb table) inline, NHWC bf16 [b,px,16]
// -> NCHW fp32 planes [b*2+oc][px].
// ---------------------------------------------------------------------------
__global__ __launch_bounds__(256) void head_k(const short* __restrict__ e3,
                                              const float* __restrict__ w,
                                              const float* __restrict__ bias,
                                              const float* __restrict__ kst,
                                              float* __restrict__ hd)
{
    int pix = blockIdx.x * 256 + threadIdx.x;
    int b = pix >> 16, rem = pix & 65535;
    int y = rem >> 8, x = rem & 255;
    float ka[16], kb[16];
    #pragma unroll
    for (int ic = 0; ic < 16; ++ic) {
        ka[ic] = kst[2 * (b * 16 + ic)];
        kb[ic] = kst[2 * (b * 16 + ic) + 1];
    }
    float a0 = bias[0], a1 = bias[1];
    #pragma unroll
    for (int tap = 0; tap < 9; ++tap) {
        int yy = y + tap / 3 - 1, xx = x + tap % 3 - 1;
        if ((unsigned)yy >= 256u || (unsigned)xx >= 256u) continue;
        const short* p = e3 + (size_t)((b << 16) + (yy << 8) + xx) * 16;
        #pragma unroll
        for (int ic = 0; ic < 16; ++ic) {
            float v = s2f(p[ic]) * ka[ic] + kb[ic];
            v = fmaxf(v, 0.2f * v);
            a0 += v * w[ic * 9 + tap];
            a1 += v * w[(16 + ic) * 9 + tap];
        }
    }
    hd[(size_t)(b * 2) * 65536 + rem]     = a0;
    hd[(size_t)(b * 2 + 1) * 65536 + rem] = a1;
}

// ---------------------------------------------------------------------------
// Final separable 7-tap gaussian blur (replicate edges), fp32 planes.
// ---------------------------------------------------------------------------
__global__ __launch_bounds__(256) void blur7f_k(const float* __restrict__ in,
                                                float* __restrict__ out)
{
    __shared__ float raw[22 * 22];
    __shared__ float hb[22 * 16];
    const int tid = threadIdx.x;
    const int tx = (blockIdx.x & 15) << 4;
    const int ty = (blockIdx.x >> 4) << 4;
    const size_t ch = ((size_t)blockIdx.y) << 16;
    const int py = tid >> 4, px = tid & 15;

    for (int i = tid; i < 484; i += 256) {
        int y = i / 22, x = i - y * 22;
        int gy = ty + y - 3, gx = tx + x - 3;
        gy = gy < 0 ? 0 : (gy > 255 ? 255 : gy);
        gx = gx < 0 ? 0 : (gx > 255 ? 255 : gx);
        raw[i] = in[ch + (gy << 8) + gx];
    }
    __syncthreads();
    for (int i = tid; i < 352; i += 256) {
        int r = i >> 4, cc = i & 15;
        float s = 0.f;
        #pragma unroll
        for (int j = 0; j < 7; ++j) s += gw(j) * raw[r * 22 + cc + j];
        hb[i] = s;
    }
    __syncthreads();
    float s = 0.f;
    #pragma unroll
    for (int j = 0; j < 7; ++j) s += gw(j) * hb[(py + j) * 16 + px];
    out[ch + ((ty + py) << 8) + tx + px] = s;
}

// ---------------------------------------------------------------------------
extern "C" void kernel_launch(void* const* d_in, const int* in_sizes, int n_in,
                              void* d_out, int out_size, void* d_ws, size_t ws_size,
                              hipStream_t stream)
{
    const float* feat1  = (const float*)d_in[0];
    const float* feat2  = (const float*)d_in[1];
    const float* pre_w  = (const float*)d_in[2];
    const float* pre_b  = (const float*)d_in[3];
    const float* fc1_w  = (const float*)d_in[4];
    const float* fc1_g  = (const float*)d_in[5];
    const float* fc1_be = (const float*)d_in[6];
    const float* fc2_w  = (const float*)d_in[7];
    const float* fc2_b  = (const float*)d_in[8];
    const float* e1_w   = (const float*)d_in[9];
    const float* e1_g   = (const float*)d_in[10];
    const float* e1_be  = (const float*)d_in[11];
    const float* e2_w   = (const float*)d_in[12];
    const float* e2_g   = (const float*)d_in[13];
    const float* e2_be  = (const float*)d_in[14];
    const float* e3_w   = (const float*)d_in[15];
    const float* e3_g   = (const float*)d_in[16];
    const float* e3_be  = (const float*)d_in[17];
    const float* head_w = (const float*)d_in[18];
    const float* head_b = (const float*)d_in[19];
    float* out = (float*)d_out;

    const size_t NEED = 152000000;
    if (ws_size < NEED) return;

    char* ws = (char*)d_ws;
    short* T1      = (short*)(ws);
    short* T2      = (short*)(ws + 33554432);
    short* lcPad   = (short*)(ws);
    short* B1h     = (short*)(ws + 33554432);   // blurred f1, fp16 group-major
    short* featBuf = (short*)(ws + 33554432);
    short* A       = (short*)(ws + 67108864);
    short* FC1o    = (short*)(ws + 83886080);
    short* E1o     = (short*)(ws + 67108864);
    short* E2o     = (short*)(ws + 100663296);
    short* E3o     = (short*)(ws + 117440512);
    float* HD      = (float*)(ws + 125829120);
    short* preW    = (short*)(ws + 150994944);
    short* fc1W    = (short*)(ws + 151068672);
    short* fc2W    = (short*)(ws + 151363584);
    short* e1W     = (short*)(ws + 151511040);
    short* e2W     = (short*)(ws + 151658496);
    short* e3W     = (short*)(ws + 151695360);
    float* sums0   = (float*)(ws + 151704576);
    float* sums1   = (float*)(ws + 151708672);
    float* sums2   = (float*)(ws + 151712768);
    float* sums3   = (float*)(ws + 151716864);
    float* stats0  = (float*)(ws + 151720960);
    float* stats1  = (float*)(ws + 151725056);
    float* stats2  = (float*)(ws + 151729152);
    float* stats3  = (float*)(ws + 151733248);
    float* LS      = (float*)(ws + 151737344);

    hipMemsetAsync(ws + 151704576, 0, 32784, stream);

    transpose_k<<<dim3(1024, 4), 256, 0, stream>>>(feat1, T1);
    transpose_k<<<dim3(1024, 4), 256, 0, stream>>>(feat2, T2);

    repack2_k<<<144, 256, 0, stream>>>(pre_w, preW, 64, 64, 64);
    repack2_k<<<576, 256, 0, stream>>>(fc1_w, fc1W, 128, 128, 128);
    repack2_k<<<288, 256, 0, stream>>>(fc2_w, fc2W, 64, 128, 128);
    repack2_k<<<288, 256, 0, stream>>>(e1_w, e1W, 64, 113, 128);
    repack2_k<<<72, 256, 0, stream>>>(e2_w, e2W, 32, 64, 64);
    repack2_k<<<18, 256, 0, stream>>>(e3_w, e3W, 16, 32, 32);

    // pre conv (cout=64): WX=2,WY=2,NOC=2 -> 128px x 64oc blocks
    convmfma_k<1, 64, 2, 2, 2, 4, 0><<<dim3(512, 1, 4), 256, 0, stream>>>(
        T1, T1, 64, 64, 64, preW, pre_b, A, 128, 0, 0, nullptr);
    convmfma_k<1, 64, 2, 2, 2, 4, 0><<<dim3(512, 1, 4), 256, 0, stream>>>(
        T2, T2, 64, 64, 64, preW, pre_b, A, 128, 64, 0, nullptr);

    // blur f1 -> fp16 planes, then local correlation (un-normalized lc)
    blur_k<<<dim3(2048, 4), 256, 0, stream>>>(A, B1h);
    corr2_k<<<dim3(256, 4), 256, 0, stream>>>(A, B1h, lcPad, LS);

    // fc1 (cout=128): batch-phased (FC1o[b] aliases A[b+1]); output pre-norm
    for (int b = 3; b >= 0; --b)
        convmfma_k<1, 128, 2, 2, 4, 4, 0><<<dim3(512, 1, 1), 256, 0, stream>>>(
            A, A, 128, 128, 128, fc1W, nullptr, FC1o, 128, 0, b, nullptr);
    in_stats_nhwc_k<<<dim3(128, 4), 256, 0, stream>>>(FC1o, sums0, 128, 7);
    in_finalize_k<<<2, 256, 0, stream>>>(sums0, stats0, fc1_g, fc1_be, 7, 512);

    // fc2 (cout=64): stages FC1o with IN+lrelu (MODE1, stats0)
    convmfma_k<1, 128, 2, 2, 2, 4, 1><<<dim3(512, 1, 4), 256, 0, stream>>>(
        FC1o, FC1o, 128, 128, 128, fc2W, fc2_b, featBuf, 64, 0, 0, stats0);

    // e1 (cout=64): concat(featBuf, lcPad); lc scale applied in staging (MODE2)
    convmfma_k<1, 128, 2, 2, 2, 4, 2><<<dim3(512, 1, 4), 256, 0, stream>>>(
        featBuf, lcPad, 64, 64, 64, e1W, nullptr, E1o, 64, 0, 0, LS);
    in_stats_nhwc_k<<<dim3(128, 4), 256, 0, stream>>>(E1o, sums1, 64, 6);
    in_finalize_k<<<1, 256, 0, stream>>>(sums1, stats1, e1_g, e1_be, 6, 256);

    // e2 (cout=32): dil=2; stages E1o with IN+lrelu (stats1)
    convmfma_k<2, 64, 2, 2, 1, 4, 1><<<dim3(512, 1, 4), 256, 0, stream>>>(
        E1o, E1o, 64, 64, 64, e2W, nullptr, E2o, 32, 0, 0, stats1);
    in_stats_nhwc_k<<<dim3(128, 4), 256, 0, stream>>>(E2o, sums2, 32, 5);
    in_finalize_k<<<1, 256, 0, stream>>>(sums2, stats2, e2_g, e2_be, 5, 128);

    // e3 (cout=16): dil=4; stages E2o with IN+lrelu (stats2)
    convmfma_k<4, 32, 4, 1, 1, 4, 1><<<dim3(256, 1, 4), 256, 0, stream>>>(
        E2o, E2o, 32, 32, 32, e3W, nullptr, E3o, 16, 0, 0, stats2);
    in_stats_nhwc_k<<<dim3(128, 4), 256, 0, stream>>>(E3o, sums3, 16, 4);
    in_finalize_k<<<1, 256, 0, stream>>>(sums3, stats3, e3_g, e3_be, 4, 64);

    // head applies e3's IN+lrelu inline
    head_k<<<1024, 256, 0, stream>>>(E3o, head_w, head_b, stats3, HD);
    blur7f_k<<<dim3(256, 8), 256, 0, stream>>>(HD, out);
}

// Round 7
// 910.484 us; speedup vs baseline: 2.8524x; 1.0605x over previous
//
#include <hip/hip_runtime.h>
#include <hip/hip_bf16.h>

// ---------------------------------------------------------------------------
// DispEstimator pipeline, MFMA bf16 implicit-GEMM (R14).
// R14: convmfma_k gets a T14 async-stage split — next row's global loads are
// issued into registers BEFORE the current row's MFMA phase (HBM latency and
// the MODE-transform VALU hide under compute); transform+ds_write happen
// after the barrier. fc1 moved to G=2 tiles (1024 blocks -> 4 blocks/CU; its
// z=1 batch-phased launches were capped at 2 blocks/CU with 512 blocks).
// ---------------------------------------------------------------------------

typedef __attribute__((ext_vector_type(8))) short short8;
typedef __attribute__((ext_vector_type(4))) float f32x4;
typedef _Float16 f16x8 __attribute__((ext_vector_type(8)));

__device__ __forceinline__ float s2f(short s) {
    unsigned int u = ((unsigned int)(unsigned short)s) << 16;
    float f; __builtin_memcpy(&f, &u, 4); return f;
}
__device__ __forceinline__ short f2s(float f) {
    __hip_bfloat16 h = __float2bfloat16(f);
    short s; __builtin_memcpy(&s, &h, 2); return s;
}
__device__ __forceinline__ short f2h(float f) {
    _Float16 h = (_Float16)f;
    short s; __builtin_memcpy(&s, &h, 2); return s;
}

__device__ __forceinline__ float gw(int j) {
    const float G[7] = {0.0366329f, 0.1112808f, 0.2167453f, 0.2706821f,
                        0.2167453f, 0.1112808f, 0.0366329f};
    return G[j];
}

// ---------------------------------------------------------------------------
// NCHW fp32 -> NHWC bf16 transpose. grid (1024, B), block 256.
// ---------------------------------------------------------------------------
__global__ __launch_bounds__(256) void transpose_k(const float* __restrict__ in,
                                                   short* __restrict__ out)
{
    __shared__ float t[64][65];
    const int b = blockIdx.y;
    const int px0 = blockIdx.x * 64;
    #pragma unroll
    for (int k = 0; k < 16; ++k) {
        int idx = threadIdx.x + k * 256;
        int c = idx >> 6, x = idx & 63;
        t[c][x] = in[(size_t)(b * 64 + c) * 65536 + px0 + x];
    }
    __syncthreads();
    #pragma unroll
    for (int k = 0; k < 16; ++k) {
        int idx = threadIdx.x + k * 256;
        int px = idx >> 6, c = idx & 63;
        out[(size_t)(b * 65536 + px0 + px) * 64 + c] = f2s(t[c][px]);
    }
}

// ---------------------------------------------------------------------------
// Weight repack v2: [oc][cin][3][3] fp32 -> MFMA-native
// [o16][tap][cb][lane][8] bf16. Zero-padded.
// ---------------------------------------------------------------------------
__global__ __launch_bounds__(256) void repack2_k(const float* __restrict__ w,
                                                 short* __restrict__ o,
                                                 int cout, int cin, int CINP)
{
    int idx = blockIdx.x * 256 + threadIdx.x;
    int CB = CINP >> 5;
    int tot = cout * 9 * CINP;
    if (idx >= tot) return;
    int c8   = idx & 7;
    int lane = (idx >> 3) & 63;
    int rest = idx >> 9;          // ((o16*9+tap)*CB + cb)
    int cb   = rest % CB;
    int rest2 = rest / CB;
    int tap  = rest2 % 9;
    int o16  = rest2 / 9;
    int n16 = lane & 15, q = lane >> 4;
    int oc = o16 * 16 + n16;
    int ic = cb * 32 + q * 8 + c8;
    float v = (ic < cin) ? w[(size_t)(oc * cin + ic) * 9 + tap] : 0.f;
    o[idx] = f2s(v);
}

// ---------------------------------------------------------------------------
// MFMA implicit-GEMM 3x3 conv, NHWC bf16, zero pad = DIL, LDS row staging
// with async split: issue(row n+1 -> regs) precedes compute(row n); the
// transform+ds_write ("commit") lands between the barriers.
// MODE 0 plain; MODE 1 x*ka+kb + lrelu (xf=(ka,kb) table); MODE 2 scale
// ic>=splitK by 1/(xf[b]/3211264+1e-6). Zeros outside image stay zero.
// grid:(XT*256 [/8-divisible, XCD-swizzled], cout/(16*NOC*WY), nb)
// ---------------------------------------------------------------------------
template<int DIL, int CINP, int WX, int WY, int NOC, int G, int MODE>
__global__ __launch_bounds__(256) void convmfma_k(
    const short* __restrict__ srcA, const short* __restrict__ srcB,
    int splitK, int csA, int csB,
    const short* __restrict__ wgt, const float* __restrict__ bias,
    short* __restrict__ out, int OSTR, int OBASE, int b0,
    const float* __restrict__ xf)
{
    static_assert(WX * WY == 4, "4 waves per block");
    constexpr int PXW = G * 16;
    constexpr int PXB = PXW * WX;
    constexpr int XT  = 256 / PXB;
    constexpr int CB  = CINP / 32;
    constexpr int UQ  = CINP / 8;       // 16B units per px
    constexpr int LUQ = (UQ == 16) ? 4 : ((UQ == 8) ? 3 : 2);
    static_assert(UQ == (1 << LUQ), "UQ must be 4/8/16");
    constexpr int UPX = UQ + 1;         // padded px stride (units)
    constexpr int WPX = PXB + 2 * DIL;  // staged px incl. halo
    constexpr int NTOT = WPX * UQ;
    constexpr int NIT  = (NTOT + 255) / 256;

    __shared__ __align__(16) short lds[WPX * UPX * 8];

    const int tid  = threadIdx.x;
    const int lane = tid & 63;
    const int wave = tid >> 6;
    const int q = lane >> 4, n16 = lane & 15;
    const int wx = wave % WX, wy = wave / WX;

    // bijective XCD swizzle (gridDim.x = XT*256, divisible by 8)
    constexpr int NX = XT * 256;
    const int bx = blockIdx.x;
    const int xs = (bx & 7) * (NX >> 3) + (bx >> 3);
    const int xt = xs % XT;
    const int y  = xs / XT;

    const int b  = b0 + blockIdx.z;
    const int ocWaveBase = blockIdx.y * (16 * NOC * WY) + wy * (16 * NOC);
    const int o16base = ocWaveBase >> 4;
    const int x0 = xt * PXB + wx * PXW;
    const int gxbase = xt * PXB - DIL;

    const int bC = b * CINP;
    const float sc = (MODE == 2) ? 1.f / (xf[b] * (1.f / 3211264.f) + 1e-6f) : 0.f;

    short8 stg[NIT];

    // issue: global -> regs (no transform), in-flight across the compute phase
    auto issue = [&](int yy) {
        const int rowbase = (b * 256 + yy) * 256;
        #pragma unroll
        for (int it = 0; it < NIT; ++it) {
            const int i = tid + it * 256;
            short8 v = {0, 0, 0, 0, 0, 0, 0, 0};
            if (i < NTOT) {
                const int pxl = i >> LUQ;
                const int u   = i & (UQ - 1);
                const int gx  = gxbase + pxl;
                if ((unsigned)gx < 256u) {
                    const int ic = u * 8;
                    const short* p = (ic < splitK)
                        ? srcA + (size_t)(rowbase + gx) * csA + ic
                        : srcB + (size_t)(rowbase + gx) * csB + (ic - splitK);
                    v = *reinterpret_cast<const short8*>(p);
                }
            }
            stg[it] = v;
        }
    };

    // commit: transform (MODE) + LDS write
    auto commit = [&]() {
        #pragma unroll
        for (int it = 0; it < NIT; ++it) {
            const int i = tid + it * 256;
            if (i < NTOT) {
                const int pxl = i >> LUQ;
                const int u   = i & (UQ - 1);
                short8 v = stg[it];
                if (MODE == 1) {
                    const int gx = gxbase + pxl;
                    if ((unsigned)gx < 256u) {
                        const int ic = u * 8;
                        #pragma unroll
                        for (int c = 0; c < 8; ++c) {
                            const float ka = xf[2 * (bC + ic + c)];
                            const float kb = xf[2 * (bC + ic + c) + 1];
                            float t = s2f(v[c]) * ka + kb;
                            t = fmaxf(t, 0.2f * t);
                            v[c] = f2s(t);
                        }
                    }
                } else if (MODE == 2) {
                    const int gx = gxbase + pxl;
                    const int ic = u * 8;
                    if ((unsigned)gx < 256u && ic >= splitK) {
                        #pragma unroll
                        for (int c = 0; c < 8; ++c)
                            v[c] = f2s(s2f(v[c]) * sc);
                    }
                }
                *reinterpret_cast<short8*>(&lds[(pxl * UPX + u) * 8]) = v;
            }
        }
    };

    f32x4 acc[G][NOC];
    #pragma unroll
    for (int g = 0; g < G; ++g)
        #pragma unroll
        for (int t = 0; t < NOC; ++t)
            acc[g][t] = {0.f, 0.f, 0.f, 0.f};

    {   // prologue: issue row for dyi=0
        const int yy0 = y - DIL;
        if ((unsigned)yy0 < 256u) issue(yy0);
    }

    for (int dyi = 0; dyi < 3; ++dyi) {
        const int yy = y + (dyi - 1) * DIL;
        const bool rowok = ((unsigned)yy < 256u);   // block-uniform
        __syncthreads();                            // prev readers done
        if (rowok) commit();
        __syncthreads();                            // stage visible
        if (dyi < 2) {                              // issue next row EARLY
            const int yn = y + dyi * DIL;
            if ((unsigned)yn < 256u) issue(yn);
        }
        if (!rowok) continue;                       // zero contribution

        #pragma unroll
        for (int dxi = 0; dxi < 3; ++dxi) {
            const int tap = dyi * 3 + dxi;
            #pragma unroll
            for (int cb = 0; cb < CB; ++cb) {
                short8 bfr[G];
                #pragma unroll
                for (int g = 0; g < G; ++g) {
                    const int pxl = wx * PXW + g * 16 + n16 + dxi * DIL;
                    bfr[g] = *reinterpret_cast<const short8*>(
                        &lds[(pxl * UPX + cb * 4 + q) * 8]);
                }
                #pragma unroll
                for (int t = 0; t < NOC; ++t) {
                    short8 a = *reinterpret_cast<const short8*>(
                        wgt + ((((size_t)(o16base + t) * 9 + tap) * CB + cb) * 64 + lane) * 8);
                    #pragma unroll
                    for (int g = 0; g < G; ++g)
                        acc[g][t] = __builtin_amdgcn_mfma_f32_16x16x32_bf16(
                            a, bfr[g], acc[g][t], 0, 0, 0);
                }
            }
        }
    }

    #pragma unroll
    for (int g = 0; g < G; ++g) {
        const size_t px_lin = (size_t)(b * 256 + y) * 256 + x0 + g * 16 + n16;
        #pragma unroll
        for (int t = 0; t < NOC; ++t) {
            const int oc = ocWaveBase + t * 16 + q * 4;
            f32x4 v = acc[g][t];
            if (bias) {
                v.x += bias[oc];     v.y += bias[oc + 1];
                v.z += bias[oc + 2]; v.w += bias[oc + 3];
            }
            ushort4 pk;
            pk.x = (unsigned short)f2s(v.x);
            pk.y = (unsigned short)f2s(v.y);
            pk.z = (unsigned short)f2s(v.z);
            pk.w = (unsigned short)f2s(v.w);
            *reinterpret_cast<ushort4*>(out + px_lin * OSTR + OBASE + oc) = pk;
        }
    }
}

// ---------------------------------------------------------------------------
// Instance-norm partial sums, NHWC. grid (128 slices, B), block 256.
// ---------------------------------------------------------------------------
__global__ __launch_bounds__(256) void in_stats_nhwc_k(const short* __restrict__ x,
                                                       float* __restrict__ sums,
                                                       int C, int lC)
{
    __shared__ float ls[256], lss[256];
    const int tid = threadIdx.x;
    const int b = blockIdx.y;
    const int c = tid & (C - 1);
    const int sub = tid >> lC;
    const int tpc = 256 >> lC;
    const int px0 = blockIdx.x * 512;
    float s = 0.f, ss = 0.f;
    for (int p = sub; p < 512; p += tpc) {
        float v = s2f(x[(size_t)(b * 65536 + px0 + p) * C + c]);
        s += v; ss += v * v;
    }
    ls[tid] = s; lss[tid] = ss;
    __syncthreads();
    if (tid < C) {
        float s0 = ls[tid], ss0 = lss[tid];
        for (int j = 1; j < tpc; ++j) { s0 += ls[tid + j * C]; ss0 += lss[tid + j * C]; }
        atomicAdd(sums + 2 * (b * C + tid), s0);
        atomicAdd(sums + 2 * (b * C + tid) + 1, ss0);
    }
}

// Emits (ka, kb): apply = x*ka + kb (ka = rsqrt*gamma, kb = beta - m*ka).
__global__ __launch_bounds__(256) void in_finalize_k(const float* __restrict__ sums,
                                                     float* __restrict__ stats,
                                                     const float* __restrict__ gamma,
                                                     const float* __restrict__ beta,
                                                     int lC, int n)
{
    int i = blockIdx.x * 256 + threadIdx.x;
    if (i >= n) return;
    int c = i & ((1 << lC) - 1);
    float m = sums[2 * i] * (1.f / 65536.f);
    float var = sums[2 * i + 1] * (1.f / 65536.f) - m * m;
    if (var < 0.f) var = 0.f;
    float ka = rsqrtf(var + 1e-5f) * gamma[c];
    stats[2 * i] = ka;
    stats[2 * i + 1] = beta[c] - m * ka;
}

// ---------------------------------------------------------------------------
// Separable 7x7 gaussian blur of f1 (A ch 0-63, replicate edges) -> fp16
// planes, group-major: B1[((g*4+b)<<16 | px)*8 + c]. grid (256*8, B).
// ---------------------------------------------------------------------------
__global__ __launch_bounds__(256) void blur_k(const short* __restrict__ A,
                                              short* __restrict__ B1)
{
    __shared__ __align__(16) short raw[484 * 8];    // 22x22 halo, 7.7 KB
    __shared__ __align__(16) float hb[352 * 12];    // 22 rows x 16 cols, 16.9 KB

    const int tid  = threadIdx.x;
    const int tile = blockIdx.x >> 3;
    const int g    = blockIdx.x & 7;
    const int c0   = g * 8;
    const int tx = (tile & 15) << 4;
    const int ty = (tile >> 4) << 4;
    const int b  = blockIdx.y;

    #pragma unroll
    for (int it = 0; it < 2; ++it) {
        int i = tid + it * 256;
        if (i < 484) {
            int y = i / 22, x = i - y * 22;
            int gy = ty + y - 3, gx = tx + x - 3;
            gy = gy < 0 ? 0 : (gy > 255 ? 255 : gy);
            gx = gx < 0 ? 0 : (gx > 255 ? 255 : gx);
            *reinterpret_cast<short8*>(&raw[i * 8]) =
                *reinterpret_cast<const short8*>(
                    &A[(size_t)((b << 16) + (gy << 8) + gx) * 128 + c0]);
        }
    }
    __syncthreads();

    #pragma unroll
    for (int it = 0; it < 2; ++it) {
        int i = tid + it * 256;
        if (i < 352) {                       // 22 rows x 16 core cols
            int r = i >> 4, cc = i & 15;
            float s[8];
            #pragma unroll
            for (int c = 0; c < 8; ++c) s[c] = 0.f;
            #pragma unroll
            for (int j = 0; j < 7; ++j) {
                short8 v = *reinterpret_cast<const short8*>(&raw[(r * 22 + cc + j) * 8]);
                float w = gw(j);
                #pragma unroll
                for (int c = 0; c < 8; ++c) s[c] += w * s2f(v[c]);
            }
            #pragma unroll
            for (int c = 0; c < 8; ++c) hb[i * 12 + c] = s[c];
        }
    }
    __syncthreads();

    const int py = tid >> 4, px = tid & 15;
    float s[8];
    #pragma unroll
    for (int c = 0; c < 8; ++c) s[c] = 0.f;
    #pragma unroll
    for (int j = 0; j < 7; ++j) {
        const float* hp = &hb[((py + j) * 16 + px) * 12];
        float w = gw(j);
        #pragma unroll
        for (int c = 0; c < 8; ++c) s[c] += w * hp[c];
    }
    short8 ov;
    #pragma unroll
    for (int c = 0; c < 8; ++c) ov[c] = f2h(s[c]);
    *reinterpret_cast<short8*>(
        &B1[(size_t)(((g * 4 + b) << 16) + ((ty + py) << 8) + tx + px) * 8]) = ov;
}

// ---------------------------------------------------------------------------
// Local correlation from pre-blurred f1 (fp16 planes) + f2 (A ch 64-127).
// fp16 LDS tiles (row stride 24 cells), double-buffered, v_dot2_f32_f16 SSD.
// Writes UN-normalized lc (e1 staging applies the scale).
// ---------------------------------------------------------------------------
__global__ __launch_bounds__(256, 2) void corr2_k(const short* __restrict__ A,
                                                  const short* __restrict__ B1,
                                                  short* __restrict__ lcPad,
                                                  float* __restrict__ lcsum)
{
    __shared__ __align__(16) short blh[2][22 * 24 * 8];  // 16.5 KB
    __shared__ float red[4];

    const int tid = threadIdx.x;
    const int tx = (blockIdx.x & 15) << 4;
    const int ty = (blockIdx.x >> 4) << 4;
    const int b  = blockIdx.y;
    const int py = tid >> 4, px = tid & 15;

    // Staging descriptors for cells tid and tid+256 (halo +-3).
    int y0 = tid / 22, x0c = tid - y0 * 22;
    int gy0 = ty + y0 - 3, gx0 = tx + x0c - 3;
    const bool ok0 = (gy0 >= 0 && gy0 < 256 && gx0 >= 0 && gx0 < 256);
    gy0 = gy0 < 0 ? 0 : (gy0 > 255 ? 255 : gy0);
    gx0 = gx0 < 0 ? 0 : (gx0 > 255 ? 255 : gx0);
    const int off0 = (gy0 << 8) + gx0;
    const int lc0 = y0 * 24 + x0c;

    const int c1 = tid + 256;
    int y1 = c1 / 22, x1c = c1 - y1 * 22;
    int gy1 = ty + y1 - 3, gx1 = tx + x1c - 3;
    const bool ok1 = (gy1 >= 0 && gy1 < 256 && gx1 >= 0 && gx1 < 256);
    gy1 = gy1 < 0 ? 0 : (gy1 > 255 ? 255 : gy1);
    gx1 = gx1 < 0 ? 0 : (gx1 > 255 ? 255 : gx1);
    const int off1 = (gy1 << 8) + gx1;
    const int lc1 = y1 * 24 + x1c;
    const bool has1 = (c1 < 484);

    const short* f2p = &A[(size_t)((b << 16) + ((ty + py) << 8) + tx + px) * 128 + 64];

    float acc[49];
    #pragma unroll
    for (int k = 0; k < 49; ++k) acc[k] = 0.f;

    for (int g = 0; g < 8; ++g) {
        const size_t plane = (size_t)(g * 4 + b) << 16;
        short* buf = blh[g & 1];

        {
            short8 v = *reinterpret_cast<const short8*>(&B1[(plane + off0) * 8]);
            if (!ok0) v = v ^ v;
            *reinterpret_cast<short8*>(&buf[lc0 * 8]) = v;
            if (has1) {
                short8 w = *reinterpret_cast<const short8*>(&B1[(plane + off1) * 8]);
                if (!ok1) w = w ^ w;
                *reinterpret_cast<short8*>(&buf[lc1 * 8]) = w;
            }
        }

        short8 f2raw = *reinterpret_cast<const short8*>(f2p + g * 8);
        f16x8 f2v;
        #pragma unroll
        for (int c = 0; c < 8; ++c) f2v[c] = (_Float16)s2f(f2raw[c]);

        __syncthreads();

        const short* blp = &buf[(py * 24 + px) * 8];
        #pragma unroll
        for (int i = 0; i < 7; ++i)
            #pragma unroll
            for (int j = 0; j < 7; ++j) {
                f16x8 bv = *reinterpret_cast<const f16x8*>(blp + (i * 24 + j) * 8);
                f16x8 d = f2v - bv;
                float a = acc[i * 7 + j];
#if __has_builtin(__builtin_amdgcn_fdot2)
                a = __builtin_amdgcn_fdot2(__builtin_shufflevector(d, d, 0, 1),
                                           __builtin_shufflevector(d, d, 0, 1), a, false);
                a = __builtin_amdgcn_fdot2(__builtin_shufflevector(d, d, 2, 3),
                                           __builtin_shufflevector(d, d, 2, 3), a, false);
                a = __builtin_amdgcn_fdot2(__builtin_shufflevector(d, d, 4, 5),
                                           __builtin_shufflevector(d, d, 4, 5), a, false);
                a = __builtin_amdgcn_fdot2(__builtin_shufflevector(d, d, 6, 7),
                                           __builtin_shufflevector(d, d, 6, 7), a, false);
#else
                #pragma unroll
                for (int c = 0; c < 8; ++c) {
                    float df = (float)d[c];
                    a += df * df;
                }
#endif
                acc[i * 7 + j] = a;
            }
        __syncthreads();
    }

    const size_t base = (size_t)((b << 16) + ((ty + py) << 8) + tx + px) * 64;
    float tot = 0.f;
    #pragma unroll
    for (int k = 0; k < 49; ++k) {
        float m = acc[k] * (1.f / 64.f);
        lcPad[base + k] = f2s(m);
        tot += m;
    }
    #pragma unroll
    for (int k = 49; k < 64; ++k) lcPad[base + k] = 0;

    for (int o = 32; o; o >>= 1) tot += __shfl_down(tot, o);
    if ((tid & 63) == 0) red[tid >> 6] = tot;
    __syncthreads();
    if (tid == 0) atomicAdd(lcsum + b, red[0] + red[1] + red[2] + red[3]);
}

// ---------------------------------------------------------------------------
// Head conv: applies e3's IN+lrelu (ka,kb table) inline, NHWC bf16 [b,px,16]
// -> NCHW fp32 planes [b*2+oc][px].
// ---------------------------------------------------------------------------
__global__ __launch_bounds__(256) void head_k(const short* __restrict__ e3,
                                              const float* __restrict__ w,
                                              const float* __restrict__ bias,
                                              const float* __restrict__ kst,
                                              float* __restrict__ hd)
{
    int pix = blockIdx.x * 256 + threadIdx.x;
    int b = pix >> 16, rem = pix & 65535;
    int y = rem >> 8, x = rem & 255;
    float ka[16], kb[16];
    #pragma unroll
    for (int ic = 0; ic < 16; ++ic) {
        ka[ic] = kst[2 * (b * 16 + ic)];
        kb[ic] = kst[2 * (b * 16 + ic) + 1];
    }
    float a0 = bias[0], a1 = bias[1];
    #pragma unroll
    for (int tap = 0; tap < 9; ++tap) {
        int yy = y + tap / 3 - 1, xx = x + tap % 3 - 1;
        if ((unsigned)yy >= 256u || (unsigned)xx >= 256u) continue;
        const short* p = e3 + (size_t)((b << 16) + (yy << 8) + xx) * 16;
        #pragma unroll
        for (int ic = 0; ic < 16; ++ic) {
            float v = s2f(p[ic]) * ka[ic] + kb[ic];
            v = fmaxf(v, 0.2f * v);
            a0 += v * w[ic * 9 + tap];
            a1 += v * w[(16 + ic) * 9 + tap];
        }
    }
    hd[(size_t)(b * 2) * 65536 + rem]     = a0;
    hd[(size_t)(b * 2 + 1) * 65536 + rem] = a1;
}

// ---------------------------------------------------------------------------
// Final separable 7-tap gaussian blur (replicate edges), fp32 planes.
// ---------------------------------------------------------------------------
__global__ __launch_bounds__(256) void blur7f_k(const float* __restrict__ in,
                                                float* __restrict__ out)
{
    __shared__ float raw[22 * 22];
    __shared__ float hb[22 * 16];
    const int tid = threadIdx.x;
    const int tx = (blockIdx.x & 15) << 4;
    const int ty = (blockIdx.x >> 4) << 4;
    const size_t ch = ((size_t)blockIdx.y) << 16;
    const int py = tid >> 4, px = tid & 15;

    for (int i = tid; i < 484; i += 256) {
        int y = i / 22, x = i - y * 22;
        int gy = ty + y - 3, gx = tx + x - 3;
        gy = gy < 0 ? 0 : (gy > 255 ? 255 : gy);
        gx = gx < 0 ? 0 : (gx > 255 ? 255 : gx);
        raw[i] = in[ch + (gy << 8) + gx];
    }
    __syncthreads();
    for (int i = tid; i < 352; i += 256) {
        int r = i >> 4, cc = i & 15;
        float s = 0.f;
        #pragma unroll
        for (int j = 0; j < 7; ++j) s += gw(j) * raw[r * 22 + cc + j];
        hb[i] = s;
    }
    __syncthreads();
    float s = 0.f;
    #pragma unroll
    for (int j = 0; j < 7; ++j) s += gw(j) * hb[(py + j) * 16 + px];
    out[ch + ((ty + py) << 8) + tx + px] = s;
}

// ---------------------------------------------------------------------------
extern "C" void kernel_launch(void* const* d_in, const int* in_sizes, int n_in,
                              void* d_out, int out_size, void* d_ws, size_t ws_size,
                              hipStream_t stream)
{
    const float* feat1  = (const float*)d_in[0];
    const float* feat2  = (const float*)d_in[1];
    const float* pre_w  = (const float*)d_in[2];
    const float* pre_b  = (const float*)d_in[3];
    const float* fc1_w  = (const float*)d_in[4];
    const float* fc1_g  = (const float*)d_in[5];
    const float* fc1_be = (const float*)d_in[6];
    const float* fc2_w  = (const float*)d_in[7];
    const float* fc2_b  = (const float*)d_in[8];
    const float* e1_w   = (const float*)d_in[9];
    const float* e1_g   = (const float*)d_in[10];
    const float* e1_be  = (const float*)d_in[11];
    const float* e2_w   = (const float*)d_in[12];
    const float* e2_g   = (const float*)d_in[13];
    const float* e2_be  = (const float*)d_in[14];
    const float* e3_w   = (const float*)d_in[15];
    const float* e3_g   = (const float*)d_in[16];
    const float* e3_be  = (const float*)d_in[17];
    const float* head_w = (const float*)d_in[18];
    const float* head_b = (const float*)d_in[19];
    float* out = (float*)d_out;

    const size_t NEED = 152000000;
    if (ws_size < NEED) return;

    char* ws = (char*)d_ws;
    short* T1      = (short*)(ws);
    short* T2      = (short*)(ws + 33554432);
    short* lcPad   = (short*)(ws);
    short* B1h     = (short*)(ws + 33554432);   // blurred f1, fp16 group-major
    short* featBuf = (short*)(ws + 33554432);
    short* A       = (short*)(ws + 67108864);
    short* FC1o    = (short*)(ws + 83886080);
    short* E1o     = (short*)(ws + 67108864);
    short* E2o     = (short*)(ws + 100663296);
    short* E3o     = (short*)(ws + 117440512);
    float* HD      = (float*)(ws + 125829120);
    short* preW    = (short*)(ws + 150994944);
    short* fc1W    = (short*)(ws + 151068672);
    short* fc2W    = (short*)(ws + 151363584);
    short* e1W     = (short*)(ws + 151511040);
    short* e2W     = (short*)(ws + 151658496);
    short* e3W     = (short*)(ws + 151695360);
    float* sums0   = (float*)(ws + 151704576);
    float* sums1   = (float*)(ws + 151708672);
    float* sums2   = (float*)(ws + 151712768);
    float* sums3   = (float*)(ws + 151716864);
    float* stats0  = (float*)(ws + 151720960);
    float* stats1  = (float*)(ws + 151725056);
    float* stats2  = (float*)(ws + 151729152);
    float* stats3  = (float*)(ws + 151733248);
    float* LS      = (float*)(ws + 151737344);

    hipMemsetAsync(ws + 151704576, 0, 32784, stream);

    transpose_k<<<dim3(1024, 4), 256, 0, stream>>>(feat1, T1);
    transpose_k<<<dim3(1024, 4), 256, 0, stream>>>(feat2, T2);

    repack2_k<<<144, 256, 0, stream>>>(pre_w, preW, 64, 64, 64);
    repack2_k<<<576, 256, 0, stream>>>(fc1_w, fc1W, 128, 128, 128);
    repack2_k<<<288, 256, 0, stream>>>(fc2_w, fc2W, 64, 128, 128);
    repack2_k<<<288, 256, 0, stream>>>(e1_w, e1W, 64, 113, 128);
    repack2_k<<<72, 256, 0, stream>>>(e2_w, e2W, 32, 64, 64);
    repack2_k<<<18, 256, 0, stream>>>(e3_w, e3W, 16, 32, 32);

    // pre conv (cout=64): WX=2,WY=2,NOC=2 -> 128px x 64oc blocks
    convmfma_k<1, 64, 2, 2, 2, 4, 0><<<dim3(512, 1, 4), 256, 0, stream>>>(
        T1, T1, 64, 64, 64, preW, pre_b, A, 128, 0, 0, nullptr);
    convmfma_k<1, 64, 2, 2, 2, 4, 0><<<dim3(512, 1, 4), 256, 0, stream>>>(
        T2, T2, 64, 64, 64, preW, pre_b, A, 128, 64, 0, nullptr);

    // blur f1 -> fp16 planes, then local correlation (un-normalized lc)
    blur_k<<<dim3(2048, 4), 256, 0, stream>>>(A, B1h);
    corr2_k<<<dim3(256, 4), 256, 0, stream>>>(A, B1h, lcPad, LS);

    // fc1 (cout=128): batch-phased (FC1o[b] aliases A[b+1]); G=2 -> 1024
    // blocks per launch (4 blocks/CU; G=4's 512 blocks capped at 2/CU)
    for (int b = 3; b >= 0; --b)
        convmfma_k<1, 128, 2, 2, 4, 2, 0><<<dim3(1024, 1, 1), 256, 0, stream>>>(
            A, A, 128, 128, 128, fc1W, nullptr, FC1o, 128, 0, b, nullptr);
    in_stats_nhwc_k<<<dim3(128, 4), 256, 0, stream>>>(FC1o, sums0, 128, 7);
    in_finalize_k<<<2, 256, 0, stream>>>(sums0, stats0, fc1_g, fc1_be, 7, 512);

    // fc2 (cout=64): stages FC1o with IN+lrelu (MODE1, stats0)
    convmfma_k<1, 128, 2, 2, 2, 4, 1><<<dim3(512, 1, 4), 256, 0, stream>>>(
        FC1o, FC1o, 128, 128, 128, fc2W, fc2_b, featBuf, 64, 0, 0, stats0);

    // e1 (cout=64): concat(featBuf, lcPad); lc scale applied in staging (MODE2)
    convmfma_k<1, 128, 2, 2, 2, 4, 2><<<dim3(512, 1, 4), 256, 0, stream>>>(
        featBuf, lcPad, 64, 64, 64, e1W, nullptr, E1o, 64, 0, 0, LS);
    in_stats_nhwc_k<<<dim3(128, 4), 256, 0, stream>>>(E1o, sums1, 64, 6);
    in_finalize_k<<<1, 256, 0, stream>>>(sums1, stats1, e1_g, e1_be, 6, 256);

    // e2 (cout=32): dil=2; stages E1o with IN+lrelu (stats1)
    convmfma_k<2, 64, 2, 2, 1, 4, 1><<<dim3(512, 1, 4), 256, 0, stream>>>(
        E1o, E1o, 64, 64, 64, e2W, nullptr, E2o, 32, 0, 0, stats1);
    in_stats_nhwc_k<<<dim3(128, 4), 256, 0, stream>>>(E2o, sums2, 32, 5);
    in_finalize_k<<<1, 256, 0, stream>>>(sums2, stats2, e2_g, e2_be, 5, 128);

    // e3 (cout=16): dil=4; stages E2o with IN+lrelu (stats2)
    convmfma_k<4, 32, 4, 1, 1, 4, 1><<<dim3(256, 1, 4), 256, 0, stream>>>(
        E2o, E2o, 32, 32, 32, e3W, nullptr, E3o, 16, 0, 0, stats2);
    in_stats_nhwc_k<<<dim3(128, 4), 256, 0, stream>>>(E3o, sums3, 16, 4);
    in_finalize_k<<<1, 256, 0, stream>>>(sums3, stats3, e3_g, e3_be, 4, 64);

    // head applies e3's IN+lrelu inline
    head_k<<<1024, 256, 0, stream>>>(E3o, head_w, head_b, stats3, HD);
    blur7f_k<<<dim3(256, 8), 256, 0, stream>>>(HD, out);
}